// Round 7
// baseline (468.065 us; speedup 1.0000x reference)
//
#include <hip/hip_runtime.h>
#include <stdint.h>

// RNN car-following, 256 sequential steps x 4096 vehicles; 8 veh/WG, 512 WGs.
// Round-11: R10 base (344us best) + ONE isolated change: SIMD role rotation
// with role held in an SGPR (readfirstlane) so it adds ZERO vector register
// pressure at the hard 128-VGPR cap.
// Why: 344us = ~3200 cy/step vs ~1400 cy bottom-up chain estimate. The 2x
// stretch matches two co-resident blocks both putting the heavy chain wave
// at wid3 -> same SIMD -> interleaved issue. R8/R9 tested rotation but were
// spill-contaminated (FETCH +2MB signature); R10 proved the base is
// spill-free. This is the clean A/B of the contention theory.
// Spill tripwire for the post-mortem: FETCH_SIZE must stay ~5.35MB.
// Chain structure (R10): ONE barrier/step; chain on role3 with swapped-conv1
// + ds_bpermute reg-transpose (no LDS round-trip for rows 11/12); off-chain:
// role0 Jpart(t+1), role1 j0(t+2)+flush, role2 row0(t+3).

#define PAST 25
#define NTW_MAX 280

typedef __attribute__((ext_vector_type(8))) short bf16x8;
typedef __attribute__((ext_vector_type(4))) float f32x4;
typedef unsigned short u16x2 __attribute__((ext_vector_type(2)));
#define MFMA16 __builtin_amdgcn_mfma_f32_16x16x32_bf16

static __device__ __forceinline__ uint32_t f2bf(float f) {
  union { float f; uint32_t u; } x; x.f = f;
  return (x.u + 0x7FFFu + ((x.u >> 16) & 1u)) >> 16;
}
static __device__ __forceinline__ float bf2f(uint32_t b) {
  union { uint32_t u; float f; } x; x.u = b << 16; return x.f;
}
// one-instruction RNE pack of two f32 -> packed bf16x2 (low=lo, high=hi)
static __device__ __forceinline__ uint32_t pkbf(float lo, float hi) {
  uint32_t r;
  asm("v_cvt_pk_bf16_f32 %0, %1, %2" : "=v"(r) : "v"(lo), "v"(hi));
  return r;
}
static __device__ __forceinline__ f32x4 bcast4(float v) { f32x4 r = {v, v, v, v}; return r; }

static __device__ __forceinline__ uint32_t pkmax(uint32_t a, uint32_t b) {
#if __has_builtin(__builtin_elementwise_max)
  union U { uint32_t w; u16x2 v; } x, y; x.w = a; y.w = b;
  x.v = __builtin_elementwise_max(x.v, y.v);
  return x.w;
#else
  uint32_t al = a << 16, bl = b << 16;
  uint32_t lo = (al > bl ? al : bl) >> 16;
  uint32_t ah = a & 0xffff0000u, bh = b & 0xffff0000u;
  uint32_t hi = ah > bh ? ah : bh;
  return lo | hi;
#endif
}
static __device__ __forceinline__ uint4 maxq(uint4 a, uint4 b) {
  uint4 r; r.x = pkmax(a.x, b.x); r.y = pkmax(a.y, b.y);
  r.z = pkmax(a.z, b.z); r.w = pkmax(a.w, b.w); return r;
}
static __device__ __forceinline__ int w21(int x) { if (x >= 21) x -= 21; if (x >= 21) x -= 21; return x; }
static __device__ __forceinline__ int w17(int x) { if (x >= 17) x -= 17; if (x >= 17) x -= 17; return x; }
static __device__ __forceinline__ void lds_fence() {
  asm volatile("s_waitcnt lgkmcnt(0)" ::: "memory");
}
// sum across each 16-lane row via DPP rotate-accumulate (row_ror 1/2/4/8).
static __device__ __forceinline__ float rsum16(float x) {
  x += __builtin_bit_cast(float, __builtin_amdgcn_update_dpp(0, __builtin_bit_cast(int, x), 0x121, 0xf, 0xf, true));
  x += __builtin_bit_cast(float, __builtin_amdgcn_update_dpp(0, __builtin_bit_cast(int, x), 0x122, 0xf, 0xf, true));
  x += __builtin_bit_cast(float, __builtin_amdgcn_update_dpp(0, __builtin_bit_cast(int, x), 0x124, 0xf, 0xf, true));
  x += __builtin_bit_cast(float, __builtin_amdgcn_update_dpp(0, __builtin_bit_cast(int, x), 0x128, 0xf, 0xf, true));
  return x;
}

union FragU { bf16x8 v; uint16_t u[8]; uint4 q; };
struct RowD { f32x4 d0, d1; };   // swapped conv1 out: lane=veh, regs=ch quad*4+r

// 2112 + 17920 + 12288 + 20480 + 8192 + 2048 + 2048 = 65088 B  (<= 65536)
struct __align__(16) SMem {
  uint32_t Xcol[8][33][2];    // x-column ring (u&31): c0 = x0hi|x1<<16, c1 = x2|x0lo<<16
  float2 lead[8][NTW_MAX];    // full lead stream (preloaded once)
  uint16_t P[24 * 8 * 32];    // pooled conv1: ring 0..20, 21/23 = row0 dbuf, 22 unused
  uint16_t O2[20 * 8 * 64];   // out2: ring 0..16, 17/18 = j0 dbuf, 19 = j10
  float2 obuf[2][8][64];      // output dbuf (flushed every 64 steps)
  f32x4 JpartA[2][64];        // jp0..jp3 partial dense acc (hf=0), dbuf by t&1
  f32x4 JpartB[2][64];        // jp0..jp3 partial dense acc (hf=1)
};

__global__ __launch_bounds__(256, 2) void rnncf_kernel(
    const float* __restrict__ lead_states, const float* __restrict__ cur_states,
    const float* __restrict__ conv1_w, const float* __restrict__ conv1_b,
    const float* __restrict__ conv2_w, const float* __restrict__ conv2_b,
    const float* __restrict__ dense2_w, const float* __restrict__ dense2_b,
    const float* __restrict__ dense1_w, const float* __restrict__ dense1_b,
    float* __restrict__ out, int nt, int ntw) {
  __shared__ SMem sm;
  const int tid = threadIdx.x;
  const int lane = tid & 63;
  const int wid = tid >> 6;           // 0..3 (HW SIMD = wid%4)
  const int n = lane & 15;
  const int quad = lane >> 4;
  const int vbase = blockIdx.x * 8;
  // role rotation in an SGPR: separates the two co-resident blocks' heavy
  // (role 3) waves onto different SIMDs; readfirstlane -> scalar branches,
  // zero extra VGPR pressure (the R8/R9 spill trigger).
  const int role = __builtin_amdgcn_readfirstlane(
      (wid + (int)((blockIdx.x ^ (blockIdx.x >> 8)) & 3)) & 3);
  // bpermute index for pooled-row reg->frag transpose: target lane l reads
  // source lane quad*16 + (l&7)  (byte address).
  const int bpidx = ((lane >> 4) << 6) | ((lane & 7) << 2);

  // ---------------- phase 0: Xcol ring + lead preload + state ----------------
  if (tid < 200) {
    int v = tid & 7, u = tid >> 3;
    const float2 l = *(const float2*)(lead_states + ((size_t)(vbase + v) * ntw + u) * 2);
    const float2 c = *(const float2*)(cur_states + ((size_t)(vbase + v) * PAST + u) * 2);
    float x0 = (l.x - c.x) * 0.005f;
    uint32_t w0 = pkbf(x0, c.y * 0.025f);
    sm.Xcol[v][u][0] = w0;
    sm.Xcol[v][u][1] = pkbf(l.y * 0.025f, x0 - bf2f(w0 & 0xffffu));
  }
#pragma unroll
  for (int v = 0; v < 8; ++v)
    for (int i = tid; i < ntw; i += 256)
      sm.lead[v][i] = *(const float2*)(lead_states + ((size_t)(vbase + v) * ntw + i) * 2);

  float pos_s = 0.f, spd_s = 0.f;
  if (role == 3 && quad < 2 && n < 4) {   // state lives on the chain wave
    int veh = quad * 4 + n;
    const float2 c = *(const float2*)(cur_states + ((size_t)(vbase + veh) * PAST + 24) * 2);
    pos_s = c.x * 0.005f; spd_s = c.y * 0.025f;
  }

  // ---------------- weight fragments ----------------
  FragU B1[2];
#pragma unroll
  for (int ct = 0; ct < 2; ++ct)
#pragma unroll
    for (int jj = 0; jj < 8; ++jj) {
      int k = quad * 8 + jj;
      int dw = k & 3, cig = (k >> 2) & 3;
      float w = 0.f;
      if (k < 16 && dw < 3) {
        int ci = (cig == 3) ? 0 : cig;
        w = conv1_w[(dw * 3 + ci) * 32 + ct * 16 + n];
      }
      B1[ct].u[jj] = (uint16_t)f2bf(w);
    }
  FragU B2[3][4];
#pragma unroll
  for (int dw = 0; dw < 3; ++dw)
#pragma unroll
    for (int ct = 0; ct < 4; ++ct)
#pragma unroll
      for (int jj = 0; jj < 8; ++jj) {
        int kap = quad * 8 + jj;
        int ci = (kap & 1) * 16 + (kap >> 1);
        B2[dw][ct].u[jj] = (uint16_t)f2bf(conv2_w[(dw * 32 + ci) * 64 + ct * 16 + n]);
      }
  FragU Bd[12];
#pragma unroll
  for (int kt = 0; kt < 12; ++kt)
#pragma unroll
    for (int jj = 0; jj < 8; ++jj) {
      int flat = kt * 32 + quad * 8 + jj;
      int jp = flat >> 6, kap = flat & 63;
      int co = (kap & 3) * 16 + (kap >> 2);
      Bd[kt].u[jj] = (uint16_t)f2bf((n < 10) ? dense2_w[(jp * 64 + co) * 10 + n] : 0.f);
    }
  // swapped conv1 bias: lane holds output channels quad*4+r (r=0..3)
  f32x4 b1q0, b1q1;
#pragma unroll
  for (int r = 0; r < 4; ++r) {
    b1q0[r] = conv1_b[quad * 4 + r];
    b1q1[r] = conv1_b[16 + quad * 4 + r];
  }
  float b2v[4];
#pragma unroll
  for (int ct = 0; ct < 4; ++ct) b2v[ct] = conv2_b[ct * 16 + n];
  const float d2bv = (n < 10) ? dense2_b[n] : 0.f;
  const float wd1v = (n < 10) ? dense1_w[n] : 0.f;
  const float bd1v = dense1_b[0];

  // ---------------- helpers ----------------
  auto pIdx = [&](int s, int veh, int ch) { return ((s * 8 + veh) * 4 + ch) * 8; };
  auto oIdx = [&](int s, int veh, int ch) { return ((s * 8 + veh) * 8 + ch) * 8; };

  auto build_x = [&](int c, int padL, int padR) -> FragU {
    int h = quad & 1, v8 = n & 7;
    uint32_t d0 = padL ? 0u : sm.Xcol[v8][(c - 1) & 31][h];
    uint32_t d1 = sm.Xcol[v8][c & 31][h];
    uint32_t d2 = padR ? 0u : sm.Xcol[v8][(c + 1) & 31][h];
    FragU a;
    a.q.x = __builtin_amdgcn_perm(d1, d0, 0x05040100u);
    a.q.y = d2 & 0xffffu;
    a.q.z = __builtin_amdgcn_perm(d1, d0, 0x07060302u);
    a.q.w = d2 >> 16;
    return a;
  };

  // swapped conv1: D = mfma(B1, X) -> lane = veh (l&7, dup at 8..15 per quad),
  // regs r = output channels quad*4+r (d0: ch<16, d1: ch>=16).
  auto conv1s_row = [&](int c, int padL, int padR) -> RowD {
    FragU a = build_x(c, padL, padR);
    RowD rd;
    rd.d0 = MFMA16(B1[0].v, a.v, b1q0, 0, 0, 0);
    rd.d1 = MFMA16(B1[1].v, a.v, b1q1, 0, 0, 0);
    return rd;
  };

  auto relumax4 = [&](const f32x4& a, const f32x4& b) -> f32x4 {
    f32x4 r;
#pragma unroll
    for (int i = 0; i < 4; ++i) r[i] = fmaxf(fmaxf(a[i], b[i]), 0.f);
    return r;
  };
  auto relu4 = [&](const f32x4& a) -> f32x4 {
    f32x4 r;
#pragma unroll
    for (int i = 0; i < 4; ++i) r[i] = fmaxf(a[i], 0.f);
    return r;
  };
  // pack pooled swapped row: word p = (ct0 ch 4q+p, ct1 ch 4q+p) = the
  // P-layout group (g = q^(v&3)) uint4, bit-identical to the legacy format.
  auto pack4 = [&](const f32x4& p0, const f32x4& p1) -> uint4 {
    uint4 w;
    w.x = pkbf(p0[0], p1[0]); w.y = pkbf(p0[1], p1[1]);
    w.z = pkbf(p0[2], p1[2]); w.w = pkbf(p0[3], p1[3]);
    return w;
  };
  auto p_store = [&](const uint4& w, int ds) {
    if (n < 8) *(uint4*)&sm.P[pIdx(ds, n, quad ^ (n & 3))] = w;
  };
  auto pool_store = [&](const RowD& A, const RowD& Bq, int ds) {
    p_store(pack4(relumax4(A.d0, Bq.d0), relumax4(A.d1, Bq.d1)), ds);
  };
  // reg->frag transpose: 4 bpermutes, shared index (== ld_P content, verified)
  auto bperm_frag = [&](const uint4& w) -> FragU {
    FragU f;
    f.q.x = (uint32_t)__builtin_amdgcn_ds_bpermute(bpidx, (int)w.x);
    f.q.y = (uint32_t)__builtin_amdgcn_ds_bpermute(bpidx, (int)w.y);
    f.q.z = (uint32_t)__builtin_amdgcn_ds_bpermute(bpidx, (int)w.z);
    f.q.w = (uint32_t)__builtin_amdgcn_ds_bpermute(bpidx, (int)w.w);
    return f;
  };

  auto ld_P = [&](int s) -> FragU {
    FragU a; a.q = *(const uint4*)&sm.P[pIdx(s, n & 7, quad ^ (n & 3))]; return a;
  };

  auto conv2_acc = [&](f32x4* acc, int slot, int dw) {
    FragU a = ld_P(slot);
#pragma unroll
    for (int ct = 0; ct < 4; ++ct) acc[ct] = MFMA16(a.v, B2[dw][ct].v, acc[ct], 0, 0, 0);
  };

  auto conv2_accf = [&](f32x4* acc, const FragU& a, int dw) {
#pragma unroll
    for (int ct = 0; ct < 4; ++ct) acc[ct] = MFMA16(a.v, B2[dw][ct].v, acc[ct], 0, 0, 0);
  };

  auto o2_write = [&](const f32x4* acc, int ds) {
    if (quad < 2) {
#pragma unroll
      for (int r = 0; r < 4; ++r) {
        int veh = quad * 4 + r;
        float m0 = fmaxf(acc[0][r], 0.f), m1 = fmaxf(acc[1][r], 0.f);
        float m2 = fmaxf(acc[2][r], 0.f), m3 = fmaxf(acc[3][r], 0.f);
        uint2 w2; w2.x = pkbf(m0, m1); w2.y = pkbf(m2, m3);
        *(uint2*)&sm.O2[oIdx(ds, veh, (n >> 1) ^ (veh & 7)) + (n & 1) * 4] = w2;
      }
    }
  };

  auto dense_jp = [&](int pa, int pb, int jp, f32x4& a0, f32x4& a1) {
#pragma unroll
    for (int hf = 0; hf < 2; ++hf) {
      uint4 qa = *(const uint4*)&sm.O2[oIdx(pa, n & 7, (hf * 4 + quad) ^ (n & 7))];
      if (pb >= 0) {
        uint4 qb = *(const uint4*)&sm.O2[oIdx(pb, n & 7, (hf * 4 + quad) ^ (n & 7))];
        qa = maxq(qa, qb);
      }
      FragU a; a.q = qa;
      if (hf == 0) a0 = MFMA16(a.v, Bd[jp * 2].v, a0, 0, 0, 0);
      else         a1 = MFMA16(a.v, Bd[jp * 2 + 1].v, a1, 0, 0, 0);
    }
  };

  auto dense_jp_pre = [&](int pa, const uint4* qpre, int jp, f32x4& a0, f32x4& a1) {
#pragma unroll
    for (int hf = 0; hf < 2; ++hf) {
      uint4 qa = *(const uint4*)&sm.O2[oIdx(pa, n & 7, (hf * 4 + quad) ^ (n & 7))];
      if (qpre) qa = maxq(qa, qpre[hf]);
      FragU a; a.q = qa;
      if (hf == 0) a0 = MFMA16(a.v, Bd[jp * 2].v, a0, 0, 0, 0);
      else         a1 = MFMA16(a.v, Bd[jp * 2 + 1].v, a1, 0, 0, 0);
    }
  };

  auto flush_out = [&](int bi, int t0, int cnt) {
    int vv = lane >> 3;
    int s0 = (lane & 7) * 8;
#pragma unroll
    for (int k = 0; k < 8; ++k) {
      int s = s0 + k;
      if (s < cnt) {
        float2 d = sm.obuf[bi][vv][s];
        *(float2*)(out + ((size_t)(vbase + vv) * nt + t0 + s) * 2) = d;
      }
    }
  };

  __syncthreads();

  // ---------------- phase 1: P ring init pos=2..21 ----------------
#pragma unroll
  for (int i = 0; i < 5; ++i) {
    int g = 2 + wid + 4 * i;
    RowD A = conv1s_row(g, 0, 0);
    RowD Bq = conv1s_row(g + 1, 0, 0);
    pool_store(A, Bq, g % 21);
  }
  __syncthreads();

  // ---------------- phase 2: O2 ring init a=2..17 ----------------
#pragma unroll
  for (int i = 0; i < 4; ++i) {
    int a = 2 + wid + 4 * i;
    f32x4 acc[4];
#pragma unroll
    for (int ct = 0; ct < 4; ++ct) acc[ct] = bcast4(b2v[ct]);
    conv2_acc(acc, a % 21, 0);
    conv2_acc(acc, (a + 2) % 21, 1);
    conv2_acc(acc, (a + 4) % 21, 2);
    o2_write(acc, a % 17);
  }
  __syncthreads();

  // ---------------- prologue A: j0(0)->17, j0(1)->18, row0(2)->21, chain accs ----
  RowD c1A = {};
  f32x4 accA[4] = {}, accB[4] = {};
  if (role == 1) {
    RowD A = conv1s_row(0, 1, 0), Bq = conv1s_row(1, 0, 0);
    pool_store(A, Bq, 23);          // scratch (row0(0))
    lds_fence();
    f32x4 aj[4];
#pragma unroll
    for (int ct = 0; ct < 4; ++ct) aj[ct] = bcast4(b2v[ct]);
    conv2_acc(aj, 23, 0); conv2_acc(aj, 2, 1); conv2_acc(aj, 4, 2);
    o2_write(aj, 17);               // j0(0)
  } else if (role == 2) {
    RowD A = conv1s_row(1, 1, 0), Bq = conv1s_row(2, 0, 0);
    pool_store(A, Bq, 1);           // scratch (row0(1)); ring slot 1 unused until step 0
    lds_fence();
    f32x4 aj[4];
#pragma unroll
    for (int ct = 0; ct < 4; ++ct) aj[ct] = bcast4(b2v[ct]);
    conv2_acc(aj, 1, 0); conv2_acc(aj, 3, 1); conv2_acc(aj, 5, 2);
    o2_write(aj, 18);               // j0(1)
  } else if (role == 0) {
    RowD A = conv1s_row(2, 1, 0), Bq = conv1s_row(3, 0, 0);
    pool_store(A, Bq, 21);          // row0(2) -> R0(even)
  } else {
#pragma unroll
    for (int ct = 0; ct < 4; ++ct) accA[ct] = bcast4(b2v[ct]);
    conv2_acc(accA, 18, 0);         // j9(0) dw0
    conv2_acc(accA, 20, 1);         // j9(0) dw1
#pragma unroll
    for (int ct = 0; ct < 4; ++ct) accB[ct] = bcast4(b2v[ct]);
    conv2_acc(accB, 20, 0);         // j10(0) dw0
    c1A = conv1s_row(22, 0, 0);
  }
  __syncthreads();

  // ---------------- prologue B: Jpart(0) ----------------
  if (role == 0) {
    f32x4 a0 = bcast4(d2bv), a1 = bcast4(0.f);
    dense_jp(17, 2, 0, a0, a1);     // jp0 = max(j0(0), j1(0))
    dense_jp(4, 6, 1, a0, a1);
    dense_jp(8, 10, 2, a0, a1);
    dense_jp(12, 14, 3, a0, a1);
    sm.JpartA[0][lane] = a0;
    sm.JpartB[0][lane] = a1;
  }
  __syncthreads();

  // ---------------- sequential steps (ONE barrier each) ----------------
  int tm21 = 0, tm17 = 0;
  for (int t = 0; t < nt; ++t) {
    const int sP22 = w21(tm21 + 22);
    const int sO16 = w17(tm17 + 16), sO18 = w17(tm17 + 18);
    const int tm21n = (tm21 + 1 == 21) ? 0 : tm21 + 1;
    const int tm17n = (tm17 + 1 == 17) ? 0 : tm17 + 1;
    const int sP18n = w21(tm21n + 18), sP20n = w21(tm21n + 20);

    if (role == 3) {
      // ---- early off-chain loads (latency hidden under conv1) ----
      f32x4 jpA = sm.JpartA[t & 1][lane];
      f32x4 jpB = sm.JpartB[t & 1][lane];
      uint4 qj8[2];
#pragma unroll
      for (int hf = 0; hf < 2; ++hf)
        qj8[hf] = *(const uint4*)&sm.O2[oIdx(sO16, n & 7, (hf * 4 + quad) ^ (n & 7))];
      FragU fA18 = ld_P(sP18n);     // for accA(t+1) dw0
      FragU fA20 = ld_P(sP20n);     // for accA(t+1) dw1 / accB(t+1) dw0
      // ---- fresh conv1 (swapped; no LDS round-trip on the chain) ----
      RowD Bq = conv1s_row(t + 23, 0, 0);     // needs col t+24 (written step t-1)
      RowD Sg = conv1s_row(t + 24, 0, 1);
      uint4 w11 = pack4(relumax4(c1A.d0, Bq.d0), relumax4(c1A.d1, Bq.d1));
      uint4 w12 = pack4(relu4(Sg.d0), relu4(Sg.d1));
      p_store(w11, sP22);                     // ring write (readers >=2 steps later)
      c1A = Bq;                               // free carry for step t+1
      FragU f11 = bperm_frag(w11);            // pooled row 11 frag (reg transpose)
      FragU f12 = bperm_frag(w12);            // pooled row 12 frag
      // ---- fresh conv2 taps (dw0/dw1 carried from last step) ----
      conv2_accf(accA, f11, 2);               // j9 complete
      conv2_accf(accB, f11, 1);
      conv2_accf(accB, f12, 2);               // j10 complete
      o2_write(accA, sO18);                   // j9 -> ring
      o2_write(accB, 19);                     // j10 -> slot 19
      lds_fence();
      // ---- fresh dense + reduce + state ----
      f32x4 acc2 = bcast4(0.f), acc3 = bcast4(0.f);
      f32x4 acc4 = bcast4(0.f), acc5 = bcast4(0.f);
      dense_jp_pre(sO18, qj8, 4, acc2, acc3);                 // jp4 = max(j8, j9)
      dense_jp_pre(19, (const uint4*)nullptr, 5, acc4, acc5); // jp5 = j10
      float s0 = fmaxf(jpA[0] + jpB[0] + acc2[0] + acc3[0] + acc4[0] + acc5[0], 0.f) * wd1v;
      float s1 = fmaxf(jpA[1] + jpB[1] + acc2[1] + acc3[1] + acc4[1] + acc5[1], 0.f) * wd1v;
      float s2 = fmaxf(jpA[2] + jpB[2] + acc2[2] + acc3[2] + acc4[2] + acc5[2], 0.f) * wd1v;
      float s3 = fmaxf(jpA[3] + jpB[3] + acc2[3] + acc3[3] + acc4[3] + acc5[3], 0.f) * wd1v;
      s0 = rsum16(s0); s1 = rsum16(s1); s2 = rsum16(s2); s3 = rsum16(s3);
      if (quad < 2 && n < 4) {
        int veh = quad * 4 + n;
        float sv = (n == 0) ? s0 : (n == 1) ? s1 : (n == 2) ? s2 : s3;
        float accv = 10.f * (sv + bd1v) - 6.f;            // (MAXA-MINA)*x + MINA
        float np_s = pos_s + 0.02f * spd_s;               // scaled pos + DT*spd
        float nsp = spd_s * 40.f + 0.1f * accv;           // raw new speed
        pos_s = np_s; spd_s = nsp * 0.025f;
        float2 o2v; o2v.x = np_s * 200.f; o2v.y = nsp;
        sm.obuf[(t >> 6) & 1][veh][t & 63] = o2v;
        int ui = t + PAST; if (ui > ntw - 1) ui = ntw - 1;   // lead read in tail (R10 style)
        float2 ln = sm.lead[veh][ui];
        float x0 = ln.x * 0.005f - np_s;
        uint32_t wlo = pkbf(x0, spd_s);
        sm.Xcol[veh][(t + PAST) & 31][0] = wlo;
        sm.Xcol[veh][(t + PAST) & 31][1] = pkbf(ln.y * 0.025f, x0 - bf2f(wlo & 0xffffu));
      }
      // ---- next-step partial accs: register MFMA tail (loads hoisted above) ----
#pragma unroll
      for (int ct = 0; ct < 4; ++ct) accA[ct] = bcast4(b2v[ct]);
      conv2_accf(accA, fA18, 0);
      conv2_accf(accA, fA20, 1);
#pragma unroll
      for (int ct = 0; ct < 4; ++ct) accB[ct] = bcast4(b2v[ct]);
      conv2_accf(accB, fA20, 0);
    } else if (role == 0) {
      // Jpart(t+1) = bias + jp0..jp3 (all operands >= 2 steps old)
      f32x4 a0 = bcast4(d2bv), a1 = bcast4(0.f);
      dense_jp(17 + ((t + 1) & 1), w17(tm17n + 2), 0, a0, a1);  // jp0 = max(j0, j1)
      dense_jp(w17(tm17n + 4), w17(tm17n + 6), 1, a0, a1);
      dense_jp(w17(tm17n + 8), w17(tm17n + 10), 2, a0, a1);
      dense_jp(w17(tm17n + 12), w17(tm17n + 14), 3, a0, a1);
      sm.JpartA[(t + 1) & 1][lane] = a0;
      sm.JpartB[(t + 1) & 1][lane] = a1;
    } else if (role == 1) {
      // j0(t+2): row0 from R0 dbuf (written by role2 last step) + old ring rows
      if ((t & 63) == 0 && t > 0) flush_out(((t >> 6) & 1) ^ 1, t - 64, 64);
      f32x4 aj[4];
#pragma unroll
      for (int ct = 0; ct < 4; ++ct) aj[ct] = bcast4(b2v[ct]);
      conv2_acc(aj, (t & 1) ? 23 : 21, 0);     // R0(t+2)
      conv2_acc(aj, w21(tm21 + 4), 1);
      conv2_acc(aj, w21(tm21 + 6), 2);
      o2_write(aj, 17 + (t & 1));              // J0(t+2)
    } else {
      // row0(t+3) -> R0 dbuf (cols t+2..t+5, all old)
      RowD A = conv1s_row(t + 3, 1, 0);
      RowD Bq = conv1s_row(t + 4, 0, 0);
      pool_store(A, Bq, (t & 1) ? 21 : 23);    // R0(t+3)
    }
    __syncthreads();

    tm21 = tm21n; tm17 = tm17n;
  }

  // final output flush
  if (role == 1) {
    int t0 = (nt - 1) & ~63;
    flush_out(((nt - 1) >> 6) & 1, t0, nt - t0);
  }
}

extern "C" void kernel_launch(void* const* d_in, const int* in_sizes, int n_in,
                              void* d_out, int out_size, void* d_ws, size_t ws_size,
                              hipStream_t stream) {
  const float* lead = (const float*)d_in[0];
  const float* cur  = (const float*)d_in[1];
  // d_in[2] = mask (unused by reference)
  const float* c1w = (const float*)d_in[3];
  const float* c1b = (const float*)d_in[4];
  const float* c2w = (const float*)d_in[5];
  const float* c2b = (const float*)d_in[6];
  const float* d2w = (const float*)d_in[7];
  const float* d2b = (const float*)d_in[8];
  const float* d1w = (const float*)d_in[9];
  const float* d1b = (const float*)d_in[10];
  float* out = (float*)d_out;

  int nveh = in_sizes[1] / (PAST * 2);   // 4096
  int ntw  = in_sizes[2] / nveh;         // nt + PAST - 1 (<= NTW_MAX)
  int nt   = ntw - PAST + 1;             // 256
  int nblocks = nveh / 8;                // 512

  rnncf_kernel<<<nblocks, 256, 0, stream>>>(lead, cur, c1w, c1b, c2w, c2b,
                                            d2w, d2b, d1w, d1b, out, nt, ntw);
}

// Round 8
// 400.534 us; speedup vs baseline: 1.1686x; 1.1686x over previous
//
#include <hip/hip_runtime.h>
#include <stdint.h>

// RNN car-following, 256 sequential steps x 4096 vehicles; 8 veh/WG, 512 WGs.
// Round-12: R10 base (344us best) + two zero-register-pressure chain tweaks:
//  (a) remove the last chain lds_fence (o2_write -> dense reads): DS ops are
//      in-order per wave, and the compiler cannot hoist the aliasing reads
//      above the writes -> the full lgkmcnt(0) drain was redundant; the
//      dense reads now issue immediately behind the writes.
//  (b) s_setprio(2) on the chain wave (helpers stay 0): biases issue/DS
//      arbitration toward the chain when all waves resume after the barrier.
// Register-pressure note (R9/R11 lesson): VGPR file is unified w/ AGPR; this
// kernel sits AT the 256/wave budget (reported 128 + accs). Any change that
// adds vector live state spills (FETCH tripwire ~5.35MB). Both tweaks here
// add zero vector registers. Role rotation is dead (2x spill-confirmed).
// Chain structure (R10): ONE barrier/step; chain on wid3 with swapped-conv1
// + ds_bpermute reg-transpose; off-chain: wid0 Jpart(t+1), wid1 j0(t+2)+
// flush, wid2 row0(t+3).

#define PAST 25
#define NTW_MAX 280

typedef __attribute__((ext_vector_type(8))) short bf16x8;
typedef __attribute__((ext_vector_type(4))) float f32x4;
typedef unsigned short u16x2 __attribute__((ext_vector_type(2)));
#define MFMA16 __builtin_amdgcn_mfma_f32_16x16x32_bf16

static __device__ __forceinline__ uint32_t f2bf(float f) {
  union { float f; uint32_t u; } x; x.f = f;
  return (x.u + 0x7FFFu + ((x.u >> 16) & 1u)) >> 16;
}
static __device__ __forceinline__ float bf2f(uint32_t b) {
  union { uint32_t u; float f; } x; x.u = b << 16; return x.f;
}
// one-instruction RNE pack of two f32 -> packed bf16x2 (low=lo, high=hi)
static __device__ __forceinline__ uint32_t pkbf(float lo, float hi) {
  uint32_t r;
  asm("v_cvt_pk_bf16_f32 %0, %1, %2" : "=v"(r) : "v"(lo), "v"(hi));
  return r;
}
static __device__ __forceinline__ f32x4 bcast4(float v) { f32x4 r = {v, v, v, v}; return r; }

static __device__ __forceinline__ uint32_t pkmax(uint32_t a, uint32_t b) {
#if __has_builtin(__builtin_elementwise_max)
  union U { uint32_t w; u16x2 v; } x, y; x.w = a; y.w = b;
  x.v = __builtin_elementwise_max(x.v, y.v);
  return x.w;
#else
  uint32_t al = a << 16, bl = b << 16;
  uint32_t lo = (al > bl ? al : bl) >> 16;
  uint32_t ah = a & 0xffff0000u, bh = b & 0xffff0000u;
  uint32_t hi = ah > bh ? ah : bh;
  return lo | hi;
#endif
}
static __device__ __forceinline__ uint4 maxq(uint4 a, uint4 b) {
  uint4 r; r.x = pkmax(a.x, b.x); r.y = pkmax(a.y, b.y);
  r.z = pkmax(a.z, b.z); r.w = pkmax(a.w, b.w); return r;
}
static __device__ __forceinline__ int w21(int x) { if (x >= 21) x -= 21; if (x >= 21) x -= 21; return x; }
static __device__ __forceinline__ int w17(int x) { if (x >= 17) x -= 17; if (x >= 17) x -= 17; return x; }
static __device__ __forceinline__ void lds_fence() {
  asm volatile("s_waitcnt lgkmcnt(0)" ::: "memory");
}
// sum across each 16-lane row via DPP rotate-accumulate (row_ror 1/2/4/8).
static __device__ __forceinline__ float rsum16(float x) {
  x += __builtin_bit_cast(float, __builtin_amdgcn_update_dpp(0, __builtin_bit_cast(int, x), 0x121, 0xf, 0xf, true));
  x += __builtin_bit_cast(float, __builtin_amdgcn_update_dpp(0, __builtin_bit_cast(int, x), 0x122, 0xf, 0xf, true));
  x += __builtin_bit_cast(float, __builtin_amdgcn_update_dpp(0, __builtin_bit_cast(int, x), 0x124, 0xf, 0xf, true));
  x += __builtin_bit_cast(float, __builtin_amdgcn_update_dpp(0, __builtin_bit_cast(int, x), 0x128, 0xf, 0xf, true));
  return x;
}

union FragU { bf16x8 v; uint16_t u[8]; uint4 q; };
struct RowD { f32x4 d0, d1; };   // swapped conv1 out: lane=veh, regs=ch quad*4+r

// 2112 + 17920 + 12288 + 20480 + 8192 + 2048 + 2048 = 65088 B  (<= 65536)
struct __align__(16) SMem {
  uint32_t Xcol[8][33][2];    // x-column ring (u&31): c0 = x0hi|x1<<16, c1 = x2|x0lo<<16
  float2 lead[8][NTW_MAX];    // full lead stream (preloaded once)
  uint16_t P[24 * 8 * 32];    // pooled conv1: ring 0..20, 21/23 = row0 dbuf, 22 unused
  uint16_t O2[20 * 8 * 64];   // out2: ring 0..16, 17/18 = j0 dbuf, 19 = j10
  float2 obuf[2][8][64];      // output dbuf (flushed every 64 steps)
  f32x4 JpartA[2][64];        // jp0..jp3 partial dense acc (hf=0), dbuf by t&1
  f32x4 JpartB[2][64];        // jp0..jp3 partial dense acc (hf=1)
};

__global__ __launch_bounds__(256, 2) void rnncf_kernel(
    const float* __restrict__ lead_states, const float* __restrict__ cur_states,
    const float* __restrict__ conv1_w, const float* __restrict__ conv1_b,
    const float* __restrict__ conv2_w, const float* __restrict__ conv2_b,
    const float* __restrict__ dense2_w, const float* __restrict__ dense2_b,
    const float* __restrict__ dense1_w, const float* __restrict__ dense1_b,
    float* __restrict__ out, int nt, int ntw) {
  __shared__ SMem sm;
  const int tid = threadIdx.x;
  const int lane = tid & 63;
  const int wid = tid >> 6;           // 0..3 (no rotation: dead end, spills)
  const int n = lane & 15;
  const int quad = lane >> 4;
  const int vbase = blockIdx.x * 8;
  // bpermute index for pooled-row reg->frag transpose: target lane l reads
  // source lane quad*16 + (l&7)  (byte address).
  const int bpidx = ((lane >> 4) << 6) | ((lane & 7) << 2);

  // ---------------- phase 0: Xcol ring + lead preload + state ----------------
  if (tid < 200) {
    int v = tid & 7, u = tid >> 3;
    const float2 l = *(const float2*)(lead_states + ((size_t)(vbase + v) * ntw + u) * 2);
    const float2 c = *(const float2*)(cur_states + ((size_t)(vbase + v) * PAST + u) * 2);
    float x0 = (l.x - c.x) * 0.005f;
    uint32_t w0 = pkbf(x0, c.y * 0.025f);
    sm.Xcol[v][u][0] = w0;
    sm.Xcol[v][u][1] = pkbf(l.y * 0.025f, x0 - bf2f(w0 & 0xffffu));
  }
#pragma unroll
  for (int v = 0; v < 8; ++v)
    for (int i = tid; i < ntw; i += 256)
      sm.lead[v][i] = *(const float2*)(lead_states + ((size_t)(vbase + v) * ntw + i) * 2);

  float pos_s = 0.f, spd_s = 0.f;
  if (wid == 3 && quad < 2 && n < 4) {   // state lives on the chain wave
    int veh = quad * 4 + n;
    const float2 c = *(const float2*)(cur_states + ((size_t)(vbase + veh) * PAST + 24) * 2);
    pos_s = c.x * 0.005f; spd_s = c.y * 0.025f;
  }

  // ---------------- weight fragments ----------------
  FragU B1[2];
#pragma unroll
  for (int ct = 0; ct < 2; ++ct)
#pragma unroll
    for (int jj = 0; jj < 8; ++jj) {
      int k = quad * 8 + jj;
      int dw = k & 3, cig = (k >> 2) & 3;
      float w = 0.f;
      if (k < 16 && dw < 3) {
        int ci = (cig == 3) ? 0 : cig;
        w = conv1_w[(dw * 3 + ci) * 32 + ct * 16 + n];
      }
      B1[ct].u[jj] = (uint16_t)f2bf(w);
    }
  FragU B2[3][4];
#pragma unroll
  for (int dw = 0; dw < 3; ++dw)
#pragma unroll
    for (int ct = 0; ct < 4; ++ct)
#pragma unroll
      for (int jj = 0; jj < 8; ++jj) {
        int kap = quad * 8 + jj;
        int ci = (kap & 1) * 16 + (kap >> 1);
        B2[dw][ct].u[jj] = (uint16_t)f2bf(conv2_w[(dw * 32 + ci) * 64 + ct * 16 + n]);
      }
  FragU Bd[12];
#pragma unroll
  for (int kt = 0; kt < 12; ++kt)
#pragma unroll
    for (int jj = 0; jj < 8; ++jj) {
      int flat = kt * 32 + quad * 8 + jj;
      int jp = flat >> 6, kap = flat & 63;
      int co = (kap & 3) * 16 + (kap >> 2);
      Bd[kt].u[jj] = (uint16_t)f2bf((n < 10) ? dense2_w[(jp * 64 + co) * 10 + n] : 0.f);
    }
  // swapped conv1 bias: lane holds output channels quad*4+r (r=0..3)
  f32x4 b1q0, b1q1;
#pragma unroll
  for (int r = 0; r < 4; ++r) {
    b1q0[r] = conv1_b[quad * 4 + r];
    b1q1[r] = conv1_b[16 + quad * 4 + r];
  }
  float b2v[4];
#pragma unroll
  for (int ct = 0; ct < 4; ++ct) b2v[ct] = conv2_b[ct * 16 + n];
  const float d2bv = (n < 10) ? dense2_b[n] : 0.f;
  const float wd1v = (n < 10) ? dense1_w[n] : 0.f;
  const float bd1v = dense1_b[0];

  // ---------------- helpers ----------------
  auto pIdx = [&](int s, int veh, int ch) { return ((s * 8 + veh) * 4 + ch) * 8; };
  auto oIdx = [&](int s, int veh, int ch) { return ((s * 8 + veh) * 8 + ch) * 8; };

  auto build_x = [&](int c, int padL, int padR) -> FragU {
    int h = quad & 1, v8 = n & 7;
    uint32_t d0 = padL ? 0u : sm.Xcol[v8][(c - 1) & 31][h];
    uint32_t d1 = sm.Xcol[v8][c & 31][h];
    uint32_t d2 = padR ? 0u : sm.Xcol[v8][(c + 1) & 31][h];
    FragU a;
    a.q.x = __builtin_amdgcn_perm(d1, d0, 0x05040100u);
    a.q.y = d2 & 0xffffu;
    a.q.z = __builtin_amdgcn_perm(d1, d0, 0x07060302u);
    a.q.w = d2 >> 16;
    return a;
  };

  // swapped conv1: D = mfma(B1, X) -> lane = veh (l&7, dup at 8..15 per quad),
  // regs r = output channels quad*4+r (d0: ch<16, d1: ch>=16).
  auto conv1s_row = [&](int c, int padL, int padR) -> RowD {
    FragU a = build_x(c, padL, padR);
    RowD rd;
    rd.d0 = MFMA16(B1[0].v, a.v, b1q0, 0, 0, 0);
    rd.d1 = MFMA16(B1[1].v, a.v, b1q1, 0, 0, 0);
    return rd;
  };

  auto relumax4 = [&](const f32x4& a, const f32x4& b) -> f32x4 {
    f32x4 r;
#pragma unroll
    for (int i = 0; i < 4; ++i) r[i] = fmaxf(fmaxf(a[i], b[i]), 0.f);
    return r;
  };
  auto relu4 = [&](const f32x4& a) -> f32x4 {
    f32x4 r;
#pragma unroll
    for (int i = 0; i < 4; ++i) r[i] = fmaxf(a[i], 0.f);
    return r;
  };
  // pack pooled swapped row: word p = (ct0 ch 4q+p, ct1 ch 4q+p) = the
  // P-layout group (g = q^(v&3)) uint4, bit-identical to the legacy format.
  auto pack4 = [&](const f32x4& p0, const f32x4& p1) -> uint4 {
    uint4 w;
    w.x = pkbf(p0[0], p1[0]); w.y = pkbf(p0[1], p1[1]);
    w.z = pkbf(p0[2], p1[2]); w.w = pkbf(p0[3], p1[3]);
    return w;
  };
  auto p_store = [&](const uint4& w, int ds) {
    if (n < 8) *(uint4*)&sm.P[pIdx(ds, n, quad ^ (n & 3))] = w;
  };
  auto pool_store = [&](const RowD& A, const RowD& Bq, int ds) {
    p_store(pack4(relumax4(A.d0, Bq.d0), relumax4(A.d1, Bq.d1)), ds);
  };
  // reg->frag transpose: 4 bpermutes, shared index (== ld_P content, verified)
  auto bperm_frag = [&](const uint4& w) -> FragU {
    FragU f;
    f.q.x = (uint32_t)__builtin_amdgcn_ds_bpermute(bpidx, (int)w.x);
    f.q.y = (uint32_t)__builtin_amdgcn_ds_bpermute(bpidx, (int)w.y);
    f.q.z = (uint32_t)__builtin_amdgcn_ds_bpermute(bpidx, (int)w.z);
    f.q.w = (uint32_t)__builtin_amdgcn_ds_bpermute(bpidx, (int)w.w);
    return f;
  };

  auto ld_P = [&](int s) -> FragU {
    FragU a; a.q = *(const uint4*)&sm.P[pIdx(s, n & 7, quad ^ (n & 3))]; return a;
  };

  auto conv2_acc = [&](f32x4* acc, int slot, int dw) {
    FragU a = ld_P(slot);
#pragma unroll
    for (int ct = 0; ct < 4; ++ct) acc[ct] = MFMA16(a.v, B2[dw][ct].v, acc[ct], 0, 0, 0);
  };

  auto conv2_accf = [&](f32x4* acc, const FragU& a, int dw) {
#pragma unroll
    for (int ct = 0; ct < 4; ++ct) acc[ct] = MFMA16(a.v, B2[dw][ct].v, acc[ct], 0, 0, 0);
  };

  auto o2_write = [&](const f32x4* acc, int ds) {
    if (quad < 2) {
#pragma unroll
      for (int r = 0; r < 4; ++r) {
        int veh = quad * 4 + r;
        float m0 = fmaxf(acc[0][r], 0.f), m1 = fmaxf(acc[1][r], 0.f);
        float m2 = fmaxf(acc[2][r], 0.f), m3 = fmaxf(acc[3][r], 0.f);
        uint2 w2; w2.x = pkbf(m0, m1); w2.y = pkbf(m2, m3);
        *(uint2*)&sm.O2[oIdx(ds, veh, (n >> 1) ^ (veh & 7)) + (n & 1) * 4] = w2;
      }
    }
  };

  auto dense_jp = [&](int pa, int pb, int jp, f32x4& a0, f32x4& a1) {
#pragma unroll
    for (int hf = 0; hf < 2; ++hf) {
      uint4 qa = *(const uint4*)&sm.O2[oIdx(pa, n & 7, (hf * 4 + quad) ^ (n & 7))];
      if (pb >= 0) {
        uint4 qb = *(const uint4*)&sm.O2[oIdx(pb, n & 7, (hf * 4 + quad) ^ (n & 7))];
        qa = maxq(qa, qb);
      }
      FragU a; a.q = qa;
      if (hf == 0) a0 = MFMA16(a.v, Bd[jp * 2].v, a0, 0, 0, 0);
      else         a1 = MFMA16(a.v, Bd[jp * 2 + 1].v, a1, 0, 0, 0);
    }
  };

  auto dense_jp_pre = [&](int pa, const uint4* qpre, int jp, f32x4& a0, f32x4& a1) {
#pragma unroll
    for (int hf = 0; hf < 2; ++hf) {
      uint4 qa = *(const uint4*)&sm.O2[oIdx(pa, n & 7, (hf * 4 + quad) ^ (n & 7))];
      if (qpre) qa = maxq(qa, qpre[hf]);
      FragU a; a.q = qa;
      if (hf == 0) a0 = MFMA16(a.v, Bd[jp * 2].v, a0, 0, 0, 0);
      else         a1 = MFMA16(a.v, Bd[jp * 2 + 1].v, a1, 0, 0, 0);
    }
  };

  auto flush_out = [&](int bi, int t0, int cnt) {
    int vv = lane >> 3;
    int s0 = (lane & 7) * 8;
#pragma unroll
    for (int k = 0; k < 8; ++k) {
      int s = s0 + k;
      if (s < cnt) {
        float2 d = sm.obuf[bi][vv][s];
        *(float2*)(out + ((size_t)(vbase + vv) * nt + t0 + s) * 2) = d;
      }
    }
  };

  __syncthreads();

  // ---------------- phase 1: P ring init pos=2..21 ----------------
#pragma unroll
  for (int i = 0; i < 5; ++i) {
    int g = 2 + wid + 4 * i;
    RowD A = conv1s_row(g, 0, 0);
    RowD Bq = conv1s_row(g + 1, 0, 0);
    pool_store(A, Bq, g % 21);
  }
  __syncthreads();

  // ---------------- phase 2: O2 ring init a=2..17 ----------------
#pragma unroll
  for (int i = 0; i < 4; ++i) {
    int a = 2 + wid + 4 * i;
    f32x4 acc[4];
#pragma unroll
    for (int ct = 0; ct < 4; ++ct) acc[ct] = bcast4(b2v[ct]);
    conv2_acc(acc, a % 21, 0);
    conv2_acc(acc, (a + 2) % 21, 1);
    conv2_acc(acc, (a + 4) % 21, 2);
    o2_write(acc, a % 17);
  }
  __syncthreads();

  // ---------------- prologue A: j0(0)->17, j0(1)->18, row0(2)->21, chain accs ----
  RowD c1A = {};
  f32x4 accA[4] = {}, accB[4] = {};
  if (wid == 1) {
    RowD A = conv1s_row(0, 1, 0), Bq = conv1s_row(1, 0, 0);
    pool_store(A, Bq, 23);          // scratch (row0(0))
    lds_fence();
    f32x4 aj[4];
#pragma unroll
    for (int ct = 0; ct < 4; ++ct) aj[ct] = bcast4(b2v[ct]);
    conv2_acc(aj, 23, 0); conv2_acc(aj, 2, 1); conv2_acc(aj, 4, 2);
    o2_write(aj, 17);               // j0(0)
  } else if (wid == 2) {
    RowD A = conv1s_row(1, 1, 0), Bq = conv1s_row(2, 0, 0);
    pool_store(A, Bq, 1);           // scratch (row0(1)); ring slot 1 unused until step 0
    lds_fence();
    f32x4 aj[4];
#pragma unroll
    for (int ct = 0; ct < 4; ++ct) aj[ct] = bcast4(b2v[ct]);
    conv2_acc(aj, 1, 0); conv2_acc(aj, 3, 1); conv2_acc(aj, 5, 2);
    o2_write(aj, 18);               // j0(1)
  } else if (wid == 0) {
    RowD A = conv1s_row(2, 1, 0), Bq = conv1s_row(3, 0, 0);
    pool_store(A, Bq, 21);          // row0(2) -> R0(even)
  } else {
#pragma unroll
    for (int ct = 0; ct < 4; ++ct) accA[ct] = bcast4(b2v[ct]);
    conv2_acc(accA, 18, 0);         // j9(0) dw0
    conv2_acc(accA, 20, 1);         // j9(0) dw1
#pragma unroll
    for (int ct = 0; ct < 4; ++ct) accB[ct] = bcast4(b2v[ct]);
    conv2_acc(accB, 20, 0);         // j10(0) dw0
    c1A = conv1s_row(22, 0, 0);
  }
  __syncthreads();

  // ---------------- prologue B: Jpart(0) ----------------
  if (wid == 0) {
    f32x4 a0 = bcast4(d2bv), a1 = bcast4(0.f);
    dense_jp(17, 2, 0, a0, a1);     // jp0 = max(j0(0), j1(0))
    dense_jp(4, 6, 1, a0, a1);
    dense_jp(8, 10, 2, a0, a1);
    dense_jp(12, 14, 3, a0, a1);
    sm.JpartA[0][lane] = a0;
    sm.JpartB[0][lane] = a1;
  }
  __syncthreads();

  // chain wave gets priority for issue/DS arbitration (helpers stay prio 0)
  if (wid == 3) __builtin_amdgcn_s_setprio(2);

  // ---------------- sequential steps (ONE barrier each) ----------------
  int tm21 = 0, tm17 = 0;
  for (int t = 0; t < nt; ++t) {
    const int sP22 = w21(tm21 + 22);
    const int sO16 = w17(tm17 + 16), sO18 = w17(tm17 + 18);
    const int tm21n = (tm21 + 1 == 21) ? 0 : tm21 + 1;
    const int tm17n = (tm17 + 1 == 17) ? 0 : tm17 + 1;
    const int sP18n = w21(tm21n + 18), sP20n = w21(tm21n + 20);

    if (wid == 3) {
      // ---- early off-chain loads (latency hidden under conv1) ----
      f32x4 jpA = sm.JpartA[t & 1][lane];
      f32x4 jpB = sm.JpartB[t & 1][lane];
      uint4 qj8[2];
#pragma unroll
      for (int hf = 0; hf < 2; ++hf)
        qj8[hf] = *(const uint4*)&sm.O2[oIdx(sO16, n & 7, (hf * 4 + quad) ^ (n & 7))];
      FragU fA18 = ld_P(sP18n);     // for accA(t+1) dw0
      FragU fA20 = ld_P(sP20n);     // for accA(t+1) dw1 / accB(t+1) dw0
      // ---- fresh conv1 (swapped; no LDS round-trip on the chain) ----
      RowD Bq = conv1s_row(t + 23, 0, 0);     // needs col t+24 (written step t-1)
      RowD Sg = conv1s_row(t + 24, 0, 1);
      uint4 w11 = pack4(relumax4(c1A.d0, Bq.d0), relumax4(c1A.d1, Bq.d1));
      uint4 w12 = pack4(relu4(Sg.d0), relu4(Sg.d1));
      p_store(w11, sP22);                     // ring write (readers >=2 steps later)
      c1A = Bq;                               // free carry for step t+1
      FragU f11 = bperm_frag(w11);            // pooled row 11 frag (reg transpose)
      FragU f12 = bperm_frag(w12);            // pooled row 12 frag
      // ---- fresh conv2 taps (dw0/dw1 carried from last step) ----
      conv2_accf(accA, f11, 2);               // j9 complete
      conv2_accf(accB, f11, 1);
      conv2_accf(accB, f12, 2);               // j10 complete
      o2_write(accA, sO18);                   // j9 -> ring
      o2_write(accB, 19);                     // j10 -> slot 19
      // NO fence: DS ops are in-order per wave; the aliasing dense reads
      // below cannot be hoisted above the writes by the compiler, and the
      // HW returns fresh data. Only the reads' own lgkmcnt gates the MFMAs.
      // ---- fresh dense + reduce + state ----
      f32x4 acc2 = bcast4(0.f), acc3 = bcast4(0.f);
      f32x4 acc4 = bcast4(0.f), acc5 = bcast4(0.f);
      dense_jp_pre(sO18, qj8, 4, acc2, acc3);                 // jp4 = max(j8, j9)
      dense_jp_pre(19, (const uint4*)nullptr, 5, acc4, acc5); // jp5 = j10
      float s0 = fmaxf(jpA[0] + jpB[0] + acc2[0] + acc3[0] + acc4[0] + acc5[0], 0.f) * wd1v;
      float s1 = fmaxf(jpA[1] + jpB[1] + acc2[1] + acc3[1] + acc4[1] + acc5[1], 0.f) * wd1v;
      float s2 = fmaxf(jpA[2] + jpB[2] + acc2[2] + acc3[2] + acc4[2] + acc5[2], 0.f) * wd1v;
      float s3 = fmaxf(jpA[3] + jpB[3] + acc2[3] + acc3[3] + acc4[3] + acc5[3], 0.f) * wd1v;
      s0 = rsum16(s0); s1 = rsum16(s1); s2 = rsum16(s2); s3 = rsum16(s3);
      if (quad < 2 && n < 4) {
        int veh = quad * 4 + n;
        float sv = (n == 0) ? s0 : (n == 1) ? s1 : (n == 2) ? s2 : s3;
        float accv = 10.f * (sv + bd1v) - 6.f;            // (MAXA-MINA)*x + MINA
        float np_s = pos_s + 0.02f * spd_s;               // scaled pos + DT*spd
        float nsp = spd_s * 40.f + 0.1f * accv;           // raw new speed
        pos_s = np_s; spd_s = nsp * 0.025f;
        float2 o2v; o2v.x = np_s * 200.f; o2v.y = nsp;
        sm.obuf[(t >> 6) & 1][veh][t & 63] = o2v;
        int ui = t + PAST; if (ui > ntw - 1) ui = ntw - 1;
        float2 ln = sm.lead[veh][ui];
        float x0 = ln.x * 0.005f - np_s;
        uint32_t wlo = pkbf(x0, spd_s);
        sm.Xcol[veh][(t + PAST) & 31][0] = wlo;
        sm.Xcol[veh][(t + PAST) & 31][1] = pkbf(ln.y * 0.025f, x0 - bf2f(wlo & 0xffffu));
      }
      // ---- next-step partial accs: register MFMA tail (loads hoisted above) ----
#pragma unroll
      for (int ct = 0; ct < 4; ++ct) accA[ct] = bcast4(b2v[ct]);
      conv2_accf(accA, fA18, 0);
      conv2_accf(accA, fA20, 1);
#pragma unroll
      for (int ct = 0; ct < 4; ++ct) accB[ct] = bcast4(b2v[ct]);
      conv2_accf(accB, fA20, 0);
    } else if (wid == 0) {
      // Jpart(t+1) = bias + jp0..jp3 (all operands >= 2 steps old)
      f32x4 a0 = bcast4(d2bv), a1 = bcast4(0.f);
      dense_jp(17 + ((t + 1) & 1), w17(tm17n + 2), 0, a0, a1);  // jp0 = max(j0, j1)
      dense_jp(w17(tm17n + 4), w17(tm17n + 6), 1, a0, a1);
      dense_jp(w17(tm17n + 8), w17(tm17n + 10), 2, a0, a1);
      dense_jp(w17(tm17n + 12), w17(tm17n + 14), 3, a0, a1);
      sm.JpartA[(t + 1) & 1][lane] = a0;
      sm.JpartB[(t + 1) & 1][lane] = a1;
    } else if (wid == 1) {
      // j0(t+2): row0 from R0 dbuf (written by wid2 last step) + old ring rows
      if ((t & 63) == 0 && t > 0) flush_out(((t >> 6) & 1) ^ 1, t - 64, 64);
      f32x4 aj[4];
#pragma unroll
      for (int ct = 0; ct < 4; ++ct) aj[ct] = bcast4(b2v[ct]);
      conv2_acc(aj, (t & 1) ? 23 : 21, 0);     // R0(t+2)
      conv2_acc(aj, w21(tm21 + 4), 1);
      conv2_acc(aj, w21(tm21 + 6), 2);
      o2_write(aj, 17 + (t & 1));              // J0(t+2)
    } else {
      // row0(t+3) -> R0 dbuf (cols t+2..t+5, all old)
      RowD A = conv1s_row(t + 3, 1, 0);
      RowD Bq = conv1s_row(t + 4, 0, 0);
      pool_store(A, Bq, (t & 1) ? 21 : 23);    // R0(t+3)
    }
    __syncthreads();

    tm21 = tm21n; tm17 = tm17n;
  }

  // final output flush
  if (wid == 1) {
    int t0 = (nt - 1) & ~63;
    flush_out(((nt - 1) >> 6) & 1, t0, nt - t0);
  }
}

extern "C" void kernel_launch(void* const* d_in, const int* in_sizes, int n_in,
                              void* d_out, int out_size, void* d_ws, size_t ws_size,
                              hipStream_t stream) {
  const float* lead = (const float*)d_in[0];
  const float* cur  = (const float*)d_in[1];
  // d_in[2] = mask (unused by reference)
  const float* c1w = (const float*)d_in[3];
  const float* c1b = (const float*)d_in[4];
  const float* c2w = (const float*)d_in[5];
  const float* c2b = (const float*)d_in[6];
  const float* d2w = (const float*)d_in[7];
  const float* d2b = (const float*)d_in[8];
  const float* d1w = (const float*)d_in[9];
  const float* d1b = (const float*)d_in[10];
  float* out = (float*)d_out;

  int nveh = in_sizes[1] / (PAST * 2);   // 4096
  int ntw  = in_sizes[2] / nveh;         // nt + PAST - 1 (<= NTW_MAX)
  int nt   = ntw - PAST + 1;             // 256
  int nblocks = nveh / 8;                // 512

  rnncf_kernel<<<nblocks, 256, 0, stream>>>(lead, cur, c1w, c1b, c2w, c2b,
                                            d2w, d2b, d1w, d1b, out, nt, ntw);
}

// Round 9
// 390.207 us; speedup vs baseline: 1.1995x; 1.0265x over previous
//
#include <hip/hip_runtime.h>
#include <stdint.h>

// RNN car-following, 256 sequential steps x 4096 vehicles; 8 veh/WG, 512 WGs.
// Round-13: ONE BARRIER PER 2 STEPS (superstep). Edge audit: the chain (wid3)
// reads only Jpart from other waves; helpers form a 3-stage pipeline
// (wid2 row0 -> wid1 j0 -> wid0 Jpart -> chain). Shifting each producer one
// step earlier makes every cross-wave edge span >= 2 steps, so the barrier
// is needed only at superstep boundaries:
//   superstep k = model steps 2k, 2k+1; chain runs both back-to-back.
//   wid0: Jpart(2k+2),(2k+3)   [ring of 4 by t&3]
//   wid1: j0(2k+4),(2k+5)      [O2 slots 17..20 by t&3] + obuf flush
//   wid2: row0(2k+6),(2k+7)    [P slots 21..24 by t&3]
// All ring-slot disjointness verified mod 21/17/4/32; freshest helper inputs
// cross exactly one barrier. LDS rebudget to fit 4-deep rings (62016B):
// lead[] split into leadx(f32)+leady(pre-converted bf16, bit-identical),
// obuf granularity 64->32 steps, P 24->25 slots, O2 20->22 slots.
// Mechanism: halves barrier count AND spreads the post-barrier DS-pipe burst
// (~60 LDS ops/block dumped at each step boundary) over 2-step windows.
// Spill tripwire: FETCH_SIZE must stay ~5.3MB (R9/R11 lesson).

#define PAST 25
#define NTW_MAX 280

typedef __attribute__((ext_vector_type(8))) short bf16x8;
typedef __attribute__((ext_vector_type(4))) float f32x4;
typedef unsigned short u16x2 __attribute__((ext_vector_type(2)));
#define MFMA16 __builtin_amdgcn_mfma_f32_16x16x32_bf16

static __device__ __forceinline__ uint32_t f2bf(float f) {
  union { float f; uint32_t u; } x; x.f = f;
  return (x.u + 0x7FFFu + ((x.u >> 16) & 1u)) >> 16;
}
static __device__ __forceinline__ float bf2f(uint32_t b) {
  union { uint32_t u; float f; } x; x.u = b << 16; return x.f;
}
// one-instruction RNE pack of two f32 -> packed bf16x2 (low=lo, high=hi)
static __device__ __forceinline__ uint32_t pkbf(float lo, float hi) {
  uint32_t r;
  asm("v_cvt_pk_bf16_f32 %0, %1, %2" : "=v"(r) : "v"(lo), "v"(hi));
  return r;
}
static __device__ __forceinline__ f32x4 bcast4(float v) { f32x4 r = {v, v, v, v}; return r; }

static __device__ __forceinline__ uint32_t pkmax(uint32_t a, uint32_t b) {
#if __has_builtin(__builtin_elementwise_max)
  union U { uint32_t w; u16x2 v; } x, y; x.w = a; y.w = b;
  x.v = __builtin_elementwise_max(x.v, y.v);
  return x.w;
#else
  uint32_t al = a << 16, bl = b << 16;
  uint32_t lo = (al > bl ? al : bl) >> 16;
  uint32_t ah = a & 0xffff0000u, bh = b & 0xffff0000u;
  uint32_t hi = ah > bh ? ah : bh;
  return lo | hi;
#endif
}
static __device__ __forceinline__ uint4 maxq(uint4 a, uint4 b) {
  uint4 r; r.x = pkmax(a.x, b.x); r.y = pkmax(a.y, b.y);
  r.z = pkmax(a.z, b.z); r.w = pkmax(a.w, b.w); return r;
}
// wraps: valid for x < 63 (w21) / x < 51 (w17)
static __device__ __forceinline__ int w21(int x) { if (x >= 21) x -= 21; if (x >= 21) x -= 21; return x; }
static __device__ __forceinline__ int w17(int x) { if (x >= 17) x -= 17; if (x >= 17) x -= 17; return x; }
// sum across each 16-lane row via DPP rotate-accumulate (row_ror 1/2/4/8).
static __device__ __forceinline__ float rsum16(float x) {
  x += __builtin_bit_cast(float, __builtin_amdgcn_update_dpp(0, __builtin_bit_cast(int, x), 0x121, 0xf, 0xf, true));
  x += __builtin_bit_cast(float, __builtin_amdgcn_update_dpp(0, __builtin_bit_cast(int, x), 0x122, 0xf, 0xf, true));
  x += __builtin_bit_cast(float, __builtin_amdgcn_update_dpp(0, __builtin_bit_cast(int, x), 0x124, 0xf, 0xf, true));
  x += __builtin_bit_cast(float, __builtin_amdgcn_update_dpp(0, __builtin_bit_cast(int, x), 0x128, 0xf, 0xf, true));
  return x;
}

union FragU { bf16x8 v; uint16_t u[8]; uint4 q; };
struct RowD { f32x4 d0, d1; };   // swapped conv1 out: lane=veh, regs=ch quad*4+r

// 2112 + 8192 + 4096 + 12800 + 22528 + 4096 + 4096 + 4096 = 62016 B
struct __align__(16) SMem {
  uint32_t Xcol[8][33][2];    // x-column ring (u&31)
  float    leadx[8][256];     // lead pos, idx = t (= ui-25), t in [0, ntw-26]
  uint16_t leady[8][256];     // f2bf(lead speed * 0.025), same idx
  uint16_t P[25 * 8 * 32];    // conv1 pairs: ring 0..20 (g%21), R0 ring 21..24 (21+(tau&3))
  uint16_t O2[22 * 8 * 64];   // ring 0..16, J0 ring 17..20 (17+(tau&3)), 21 = j10 scratch
  float2 obuf[2][8][32];      // output dbuf (flushed every 32 steps)
  f32x4 JpartA[4][64];        // jp0..jp3 partial dense acc (hf=0), ring by t&3
  f32x4 JpartB[4][64];        // (hf=1)
};

__global__ __launch_bounds__(256, 2) void rnncf_kernel(
    const float* __restrict__ lead_states, const float* __restrict__ cur_states,
    const float* __restrict__ conv1_w, const float* __restrict__ conv1_b,
    const float* __restrict__ conv2_w, const float* __restrict__ conv2_b,
    const float* __restrict__ dense2_w, const float* __restrict__ dense2_b,
    const float* __restrict__ dense1_w, const float* __restrict__ dense1_b,
    float* __restrict__ out, int nt, int ntw) {
  __shared__ SMem sm;
  const int tid = threadIdx.x;
  const int lane = tid & 63;
  const int wid = tid >> 6;           // 0..3
  const int n = lane & 15;
  const int quad = lane >> 4;
  const int vbase = blockIdx.x * 8;
  const int bpidx = ((lane >> 4) << 6) | ((lane & 7) << 2);

  // ---------------- phase 0: Xcol ring + lead preload + state ----------------
  if (tid < 200) {
    int v = tid & 7, u = tid >> 3;
    const float2 l = *(const float2*)(lead_states + ((size_t)(vbase + v) * ntw + u) * 2);
    const float2 c = *(const float2*)(cur_states + ((size_t)(vbase + v) * PAST + u) * 2);
    float x0 = (l.x - c.x) * 0.005f;
    uint32_t w0 = pkbf(x0, c.y * 0.025f);
    sm.Xcol[v][u][0] = w0;
    sm.Xcol[v][u][1] = pkbf(l.y * 0.025f, x0 - bf2f(w0 & 0xffffu));
  }
#pragma unroll
  for (int v = 0; v < 8; ++v)
    for (int i = 25 + tid; i < ntw; i += 256) {
      const float2 l = *(const float2*)(lead_states + ((size_t)(vbase + v) * ntw + i) * 2);
      sm.leadx[v][i - 25] = l.x;
      sm.leady[v][i - 25] = (uint16_t)f2bf(l.y * 0.025f);
    }

  float pos_s = 0.f, spd_s = 0.f;
  if (wid == 3 && quad < 2 && n < 4) {   // state lives on the chain wave
    int veh = quad * 4 + n;
    const float2 c = *(const float2*)(cur_states + ((size_t)(vbase + veh) * PAST + 24) * 2);
    pos_s = c.x * 0.005f; spd_s = c.y * 0.025f;
  }

  // ---------------- weight fragments ----------------
  FragU B1[2];
#pragma unroll
  for (int ct = 0; ct < 2; ++ct)
#pragma unroll
    for (int jj = 0; jj < 8; ++jj) {
      int k = quad * 8 + jj;
      int dw = k & 3, cig = (k >> 2) & 3;
      float w = 0.f;
      if (k < 16 && dw < 3) {
        int ci = (cig == 3) ? 0 : cig;
        w = conv1_w[(dw * 3 + ci) * 32 + ct * 16 + n];
      }
      B1[ct].u[jj] = (uint16_t)f2bf(w);
    }
  FragU B2[3][4];
#pragma unroll
  for (int dw = 0; dw < 3; ++dw)
#pragma unroll
    for (int ct = 0; ct < 4; ++ct)
#pragma unroll
      for (int jj = 0; jj < 8; ++jj) {
        int kap = quad * 8 + jj;
        int ci = (kap & 1) * 16 + (kap >> 1);
        B2[dw][ct].u[jj] = (uint16_t)f2bf(conv2_w[(dw * 32 + ci) * 64 + ct * 16 + n]);
      }
  FragU Bd[12];
#pragma unroll
  for (int kt = 0; kt < 12; ++kt)
#pragma unroll
    for (int jj = 0; jj < 8; ++jj) {
      int flat = kt * 32 + quad * 8 + jj;
      int jp = flat >> 6, kap = flat & 63;
      int co = (kap & 3) * 16 + (kap >> 2);
      Bd[kt].u[jj] = (uint16_t)f2bf((n < 10) ? dense2_w[(jp * 64 + co) * 10 + n] : 0.f);
    }
  f32x4 b1q0, b1q1;
#pragma unroll
  for (int r = 0; r < 4; ++r) {
    b1q0[r] = conv1_b[quad * 4 + r];
    b1q1[r] = conv1_b[16 + quad * 4 + r];
  }
  float b2v[4];
#pragma unroll
  for (int ct = 0; ct < 4; ++ct) b2v[ct] = conv2_b[ct * 16 + n];
  const float d2bv = (n < 10) ? dense2_b[n] : 0.f;
  const float wd1v = (n < 10) ? dense1_w[n] : 0.f;
  const float bd1v = dense1_b[0];

  // ---------------- helpers ----------------
  auto pIdx = [&](int s, int veh, int ch) { return ((s * 8 + veh) * 4 + ch) * 8; };
  auto oIdx = [&](int s, int veh, int ch) { return ((s * 8 + veh) * 8 + ch) * 8; };

  auto build_x = [&](int c, int padL, int padR) -> FragU {
    int h = quad & 1, v8 = n & 7;
    uint32_t d0 = padL ? 0u : sm.Xcol[v8][(c - 1) & 31][h];
    uint32_t d1 = sm.Xcol[v8][c & 31][h];
    uint32_t d2 = padR ? 0u : sm.Xcol[v8][(c + 1) & 31][h];
    FragU a;
    a.q.x = __builtin_amdgcn_perm(d1, d0, 0x05040100u);
    a.q.y = d2 & 0xffffu;
    a.q.z = __builtin_amdgcn_perm(d1, d0, 0x07060302u);
    a.q.w = d2 >> 16;
    return a;
  };

  auto conv1s_row = [&](int c, int padL, int padR) -> RowD {
    FragU a = build_x(c, padL, padR);
    RowD rd;
    rd.d0 = MFMA16(B1[0].v, a.v, b1q0, 0, 0, 0);
    rd.d1 = MFMA16(B1[1].v, a.v, b1q1, 0, 0, 0);
    return rd;
  };

  auto relumax4 = [&](const f32x4& a, const f32x4& b) -> f32x4 {
    f32x4 r;
#pragma unroll
    for (int i = 0; i < 4; ++i) r[i] = fmaxf(fmaxf(a[i], b[i]), 0.f);
    return r;
  };
  auto relu4 = [&](const f32x4& a) -> f32x4 {
    f32x4 r;
#pragma unroll
    for (int i = 0; i < 4; ++i) r[i] = fmaxf(a[i], 0.f);
    return r;
  };
  auto pack4 = [&](const f32x4& p0, const f32x4& p1) -> uint4 {
    uint4 w;
    w.x = pkbf(p0[0], p1[0]); w.y = pkbf(p0[1], p1[1]);
    w.z = pkbf(p0[2], p1[2]); w.w = pkbf(p0[3], p1[3]);
    return w;
  };
  auto p_store = [&](const uint4& w, int ds) {
    if (n < 8) *(uint4*)&sm.P[pIdx(ds, n, quad ^ (n & 3))] = w;
  };
  auto pool_store = [&](const RowD& A, const RowD& Bq, int ds) {
    p_store(pack4(relumax4(A.d0, Bq.d0), relumax4(A.d1, Bq.d1)), ds);
  };
  auto bperm_frag = [&](const uint4& w) -> FragU {
    FragU f;
    f.q.x = (uint32_t)__builtin_amdgcn_ds_bpermute(bpidx, (int)w.x);
    f.q.y = (uint32_t)__builtin_amdgcn_ds_bpermute(bpidx, (int)w.y);
    f.q.z = (uint32_t)__builtin_amdgcn_ds_bpermute(bpidx, (int)w.z);
    f.q.w = (uint32_t)__builtin_amdgcn_ds_bpermute(bpidx, (int)w.w);
    return f;
  };

  auto ld_P = [&](int s) -> FragU {
    FragU a; a.q = *(const uint4*)&sm.P[pIdx(s, n & 7, quad ^ (n & 3))]; return a;
  };

  auto conv2_acc = [&](f32x4* acc, int slot, int dw) {
    FragU a = ld_P(slot);
#pragma unroll
    for (int ct = 0; ct < 4; ++ct) acc[ct] = MFMA16(a.v, B2[dw][ct].v, acc[ct], 0, 0, 0);
  };

  auto conv2_accf = [&](f32x4* acc, const FragU& a, int dw) {
#pragma unroll
    for (int ct = 0; ct < 4; ++ct) acc[ct] = MFMA16(a.v, B2[dw][ct].v, acc[ct], 0, 0, 0);
  };

  auto o2_write = [&](const f32x4* acc, int ds) {
    if (quad < 2) {
#pragma unroll
      for (int r = 0; r < 4; ++r) {
        int veh = quad * 4 + r;
        float m0 = fmaxf(acc[0][r], 0.f), m1 = fmaxf(acc[1][r], 0.f);
        float m2 = fmaxf(acc[2][r], 0.f), m3 = fmaxf(acc[3][r], 0.f);
        uint2 w2; w2.x = pkbf(m0, m1); w2.y = pkbf(m2, m3);
        *(uint2*)&sm.O2[oIdx(ds, veh, (n >> 1) ^ (veh & 7)) + (n & 1) * 4] = w2;
      }
    }
  };

  auto dense_jp = [&](int pa, int pb, int jp, f32x4& a0, f32x4& a1) {
#pragma unroll
    for (int hf = 0; hf < 2; ++hf) {
      uint4 qa = *(const uint4*)&sm.O2[oIdx(pa, n & 7, (hf * 4 + quad) ^ (n & 7))];
      if (pb >= 0) {
        uint4 qb = *(const uint4*)&sm.O2[oIdx(pb, n & 7, (hf * 4 + quad) ^ (n & 7))];
        qa = maxq(qa, qb);
      }
      FragU a; a.q = qa;
      if (hf == 0) a0 = MFMA16(a.v, Bd[jp * 2].v, a0, 0, 0, 0);
      else         a1 = MFMA16(a.v, Bd[jp * 2 + 1].v, a1, 0, 0, 0);
    }
  };

  auto dense_jp_pre = [&](int pa, const uint4* qpre, int jp, f32x4& a0, f32x4& a1) {
#pragma unroll
    for (int hf = 0; hf < 2; ++hf) {
      uint4 qa = *(const uint4*)&sm.O2[oIdx(pa, n & 7, (hf * 4 + quad) ^ (n & 7))];
      if (qpre) qa = maxq(qa, qpre[hf]);
      FragU a; a.q = qa;
      if (hf == 0) a0 = MFMA16(a.v, Bd[jp * 2].v, a0, 0, 0, 0);
      else         a1 = MFMA16(a.v, Bd[jp * 2 + 1].v, a1, 0, 0, 0);
    }
  };

  auto flush_out = [&](int bi, int t0, int cnt) {   // 32-step blocks
    int vv = lane >> 3;
    int s0 = (lane & 7) * 4;
#pragma unroll
    for (int kk = 0; kk < 4; ++kk) {
      int s = s0 + kk;
      if (s < cnt) {
        float2 d = sm.obuf[bi][vv][s];
        *(float2*)(out + ((size_t)(vbase + vv) * nt + t0 + s) * 2) = d;
      }
    }
  };

  __syncthreads();

  // ---------------- phase 1: P ring init pairs g=2..21 ----------------
#pragma unroll
  for (int i = 0; i < 5; ++i) {
    int g = 2 + wid + 4 * i;
    RowD A = conv1s_row(g, 0, 0);
    RowD Bq = conv1s_row(g + 1, 0, 0);
    pool_store(A, Bq, g % 21);
  }
  __syncthreads();

  // ---------------- phase 2: O2 ring init a=2..17 ----------------
#pragma unroll
  for (int i = 0; i < 4; ++i) {
    int a = 2 + wid + 4 * i;
    f32x4 acc[4];
#pragma unroll
    for (int ct = 0; ct < 4; ++ct) acc[ct] = bcast4(b2v[ct]);
    conv2_acc(acc, a % 21, 0);
    conv2_acc(acc, (a + 2) % 21, 1);
    conv2_acc(acc, (a + 4) % 21, 2);
    o2_write(acc, a % 17);
  }
  __syncthreads();

  // ---------------- prologue ----------------
  RowD c1A = {};
  f32x4 accA[4] = {}, accB[4] = {};
  // ProA: R0(0)->P23, R0(1)->P24
  if (wid == 0) {
    RowD A = conv1s_row(0, 1, 0), Bq = conv1s_row(1, 0, 0);
    pool_store(A, Bq, 23);
  } else if (wid == 1) {
    RowD A = conv1s_row(1, 1, 0), Bq = conv1s_row(2, 0, 0);
    pool_store(A, Bq, 24);
  }
  __syncthreads();
  // ProB: j0(0)->O2[17], j0(1)->O2[18], R0(4)->P21, R0(5)->P22
  if (wid == 0) {
    f32x4 aj[4];
#pragma unroll
    for (int ct = 0; ct < 4; ++ct) aj[ct] = bcast4(b2v[ct]);
    conv2_acc(aj, 23, 0); conv2_acc(aj, 2, 1); conv2_acc(aj, 4, 2);
    o2_write(aj, 17);
  } else if (wid == 1) {
    f32x4 aj[4];
#pragma unroll
    for (int ct = 0; ct < 4; ++ct) aj[ct] = bcast4(b2v[ct]);
    conv2_acc(aj, 24, 0); conv2_acc(aj, 3, 1); conv2_acc(aj, 5, 2);
    o2_write(aj, 18);
  } else if (wid == 2) {
    RowD A = conv1s_row(4, 1, 0), Bq = conv1s_row(5, 0, 0);
    pool_store(A, Bq, 21);
  } else {
    RowD A = conv1s_row(5, 1, 0), Bq = conv1s_row(6, 0, 0);
    pool_store(A, Bq, 22);
  }
  __syncthreads();
  // ProC: Jpart(0)->Jp[0], Jpart(1)->Jp[1], R0(2)->P23, R0(3)->P24
  if (wid == 0) {
    f32x4 a0 = bcast4(d2bv), a1 = bcast4(0.f);
    dense_jp(17, 2, 0, a0, a1);
    dense_jp(4, 6, 1, a0, a1);
    dense_jp(8, 10, 2, a0, a1);
    dense_jp(12, 14, 3, a0, a1);
    sm.JpartA[0][lane] = a0; sm.JpartB[0][lane] = a1;
  } else if (wid == 1) {
    f32x4 a0 = bcast4(d2bv), a1 = bcast4(0.f);
    dense_jp(18, 3, 0, a0, a1);
    dense_jp(5, 7, 1, a0, a1);
    dense_jp(9, 11, 2, a0, a1);
    dense_jp(13, 15, 3, a0, a1);
    sm.JpartA[1][lane] = a0; sm.JpartB[1][lane] = a1;
  } else if (wid == 2) {
    RowD A = conv1s_row(2, 1, 0), Bq = conv1s_row(3, 0, 0);
    pool_store(A, Bq, 23);
  } else {
    RowD A = conv1s_row(3, 1, 0), Bq = conv1s_row(4, 0, 0);
    pool_store(A, Bq, 24);
  }
  __syncthreads();
  // ProD: j0(2)->O2[19], j0(3)->O2[20], chain accs + c1A
  if (wid == 0) {
    f32x4 aj[4];
#pragma unroll
    for (int ct = 0; ct < 4; ++ct) aj[ct] = bcast4(b2v[ct]);
    conv2_acc(aj, 23, 0); conv2_acc(aj, 4, 1); conv2_acc(aj, 6, 2);
    o2_write(aj, 19);
  } else if (wid == 1) {
    f32x4 aj[4];
#pragma unroll
    for (int ct = 0; ct < 4; ++ct) aj[ct] = bcast4(b2v[ct]);
    conv2_acc(aj, 24, 0); conv2_acc(aj, 5, 1); conv2_acc(aj, 7, 2);
    o2_write(aj, 20);
  } else if (wid == 3) {
#pragma unroll
    for (int ct = 0; ct < 4; ++ct) accA[ct] = bcast4(b2v[ct]);
    conv2_acc(accA, 18, 0);         // j9(0) dw0 (pair g=18)
    conv2_acc(accA, 20, 1);         // j9(0) dw1 (pair g=20)
#pragma unroll
    for (int ct = 0; ct < 4; ++ct) accB[ct] = bcast4(b2v[ct]);
    conv2_acc(accB, 20, 0);         // j10(0) dw0
    c1A = conv1s_row(22, 0, 0);
  }
  __syncthreads();

  if (wid == 3) __builtin_amdgcn_s_setprio(2);

  // ---------------- supersteps: 2 model steps per barrier ----------------
  int tmA21 = 0, tmA17 = 0;     // (2k)%21, (2k)%17
  const int nsup = nt >> 1;     // nt is even (256)
  for (int k = 0; k < nsup; ++k) {
    if (wid == 3) {
#pragma unroll
      for (int d = 0; d < 2; ++d) {
        const int t = 2 * k + d;
        const int sP22 = w21(tmA21 + d + 22);
        const int sO16 = w17(tmA17 + d + 16);
        const int sO18 = w17(tmA17 + d + 18);
        const int sP18n = w21(tmA21 + d + 19);   // (t+1+18)%21
        const int sP20n = w21(tmA21 + d + 21);   // (t+1+20)%21
        // early off-chain loads
        f32x4 jpA = sm.JpartA[t & 3][lane];
        f32x4 jpB = sm.JpartB[t & 3][lane];
        uint4 qj8[2];
#pragma unroll
        for (int hf = 0; hf < 2; ++hf)
          qj8[hf] = *(const uint4*)&sm.O2[oIdx(sO16, n & 7, (hf * 4 + quad) ^ (n & 7))];
        FragU fA18 = ld_P(sP18n);
        FragU fA20 = ld_P(sP20n);
        // fresh conv1 (swapped; in-register to conv2)
        RowD Bq = conv1s_row(t + 23, 0, 0);
        RowD Sg = conv1s_row(t + 24, 0, 1);
        uint4 w11 = pack4(relumax4(c1A.d0, Bq.d0), relumax4(c1A.d1, Bq.d1));
        uint4 w12 = pack4(relu4(Sg.d0), relu4(Sg.d1));
        p_store(w11, sP22);
        c1A = Bq;
        FragU f11 = bperm_frag(w11);
        FragU f12 = bperm_frag(w12);
        conv2_accf(accA, f11, 2);               // j9 complete
        conv2_accf(accB, f11, 1);
        conv2_accf(accB, f12, 2);               // j10 complete
        o2_write(accA, sO18);                   // j9 -> ring
        o2_write(accB, 21);                     // j10 -> scratch 21
        // dense + reduce + state (DS in-order covers write->read)
        f32x4 acc2 = bcast4(0.f), acc3 = bcast4(0.f);
        f32x4 acc4 = bcast4(0.f), acc5 = bcast4(0.f);
        dense_jp_pre(sO18, qj8, 4, acc2, acc3);
        dense_jp_pre(21, (const uint4*)nullptr, 5, acc4, acc5);
        float s0 = fmaxf(jpA[0] + jpB[0] + acc2[0] + acc3[0] + acc4[0] + acc5[0], 0.f) * wd1v;
        float s1 = fmaxf(jpA[1] + jpB[1] + acc2[1] + acc3[1] + acc4[1] + acc5[1], 0.f) * wd1v;
        float s2 = fmaxf(jpA[2] + jpB[2] + acc2[2] + acc3[2] + acc4[2] + acc5[2], 0.f) * wd1v;
        float s3 = fmaxf(jpA[3] + jpB[3] + acc2[3] + acc3[3] + acc4[3] + acc5[3], 0.f) * wd1v;
        s0 = rsum16(s0); s1 = rsum16(s1); s2 = rsum16(s2); s3 = rsum16(s3);
        if (quad < 2 && n < 4) {
          int veh = quad * 4 + n;
          float sv = (n == 0) ? s0 : (n == 1) ? s1 : (n == 2) ? s2 : s3;
          float accv = 10.f * (sv + bd1v) - 6.f;
          float np_s = pos_s + 0.02f * spd_s;
          float nsp = spd_s * 40.f + 0.1f * accv;
          pos_s = np_s; spd_s = nsp * 0.025f;
          float2 o2v; o2v.x = np_s * 200.f; o2v.y = nsp;
          sm.obuf[(t >> 5) & 1][veh][t & 31] = o2v;
          int li = t; if (li > ntw - 26) li = ntw - 26;
          float lnx = sm.leadx[veh][li];
          float lny = bf2f(sm.leady[veh][li]);
          float x0 = lnx * 0.005f - np_s;
          uint32_t wlo = pkbf(x0, spd_s);
          sm.Xcol[veh][(t + PAST) & 31][0] = wlo;
          sm.Xcol[veh][(t + PAST) & 31][1] = pkbf(lny, x0 - bf2f(wlo & 0xffffu));
        }
        // next-step partial accs (register MFMA tail)
#pragma unroll
        for (int ct = 0; ct < 4; ++ct) accA[ct] = bcast4(b2v[ct]);
        conv2_accf(accA, fA18, 0);
        conv2_accf(accA, fA20, 1);
#pragma unroll
        for (int ct = 0; ct < 4; ++ct) accB[ct] = bcast4(b2v[ct]);
        conv2_accf(accB, fA20, 0);
      }
    } else if (wid == 0) {
      // Jpart(2k+2), Jpart(2k+3)
#pragma unroll
      for (int e = 0; e < 2; ++e) {
        const int tau = 2 * k + 2 + e;
        f32x4 a0 = bcast4(d2bv), a1 = bcast4(0.f);
        dense_jp(17 + (tau & 3), w17(tmA17 + 4 + e), 0, a0, a1);     // jp0 = max(j0, j1)
        dense_jp(w17(tmA17 + 6 + e), w17(tmA17 + 8 + e), 1, a0, a1);
        dense_jp(w17(tmA17 + 10 + e), w17(tmA17 + 12 + e), 2, a0, a1);
        dense_jp(w17(tmA17 + 14 + e), w17(tmA17 + 16 + e), 3, a0, a1);
        sm.JpartA[tau & 3][lane] = a0;
        sm.JpartB[tau & 3][lane] = a1;
      }
    } else if (wid == 1) {
      // obuf flush (32-step blocks) + j0(2k+4), j0(2k+5)
      if ((k & 15) == 0 && k > 0) {
        int t0 = 2 * k - 32;
        flush_out((t0 >> 5) & 1, t0, 32);
      }
#pragma unroll
      for (int e = 0; e < 2; ++e) {
        const int tau = 2 * k + 4 + e;
        f32x4 aj[4];
#pragma unroll
        for (int ct = 0; ct < 4; ++ct) aj[ct] = bcast4(b2v[ct]);
        conv2_acc(aj, 21 + (tau & 3), 0);                 // R0(tau)
        conv2_acc(aj, w21(tmA21 + 6 + e), 1);             // pair tau+2
        conv2_acc(aj, w21(tmA21 + 8 + e), 2);             // pair tau+4
        o2_write(aj, 17 + (tau & 3));                     // J0[tau&3]
      }
    } else {
      // row0(2k+6), row0(2k+7)
#pragma unroll
      for (int f = 0; f < 2; ++f) {
        const int tau = 2 * k + 6 + f;
        RowD A = conv1s_row(tau, 1, 0);
        RowD Bq = conv1s_row(tau + 1, 0, 0);
        pool_store(A, Bq, 21 + (tau & 3));
      }
    }
    __syncthreads();
    tmA21 = w21(tmA21 + 2);
    tmA17 = w17(tmA17 + 2);
  }

  // final output flush (steps [nt-32, nt-1])
  if (wid == 1) {
    int t0 = (nt - 1) & ~31;
    flush_out((t0 >> 5) & 1, t0, nt - t0);
  }
}

extern "C" void kernel_launch(void* const* d_in, const int* in_sizes, int n_in,
                              void* d_out, int out_size, void* d_ws, size_t ws_size,
                              hipStream_t stream) {
  const float* lead = (const float*)d_in[0];
  const float* cur  = (const float*)d_in[1];
  // d_in[2] = mask (unused by reference)
  const float* c1w = (const float*)d_in[3];
  const float* c1b = (const float*)d_in[4];
  const float* c2w = (const float*)d_in[5];
  const float* c2b = (const float*)d_in[6];
  const float* d2w = (const float*)d_in[7];
  const float* d2b = (const float*)d_in[8];
  const float* d1w = (const float*)d_in[9];
  const float* d1b = (const float*)d_in[10];
  float* out = (float*)d_out;

  int nveh = in_sizes[1] / (PAST * 2);   // 4096
  int ntw  = in_sizes[2] / nveh;         // nt + PAST - 1 (<= NTW_MAX)
  int nt   = ntw - PAST + 1;             // 256 (even)
  int nblocks = nveh / 8;                // 512

  rnncf_kernel<<<nblocks, 256, 0, stream>>>(lead, cur, c1w, c1b, c2w, c2b,
                                            d2w, d2b, d1w, d1b, out, nt, ntw);
}

// Round 10
// 389.822 us; speedup vs baseline: 1.2007x; 1.0010x over previous
//
#include <hip/hip_runtime.h>
#include <stdint.h>

// RNN car-following, 256 sequential steps x 4096 vehicles.
// Round-14: 16 veh/WG -> 256 blocks = ONE BLOCK PER CU, launch_bounds(256,1).
// Why: per-CU shared resources (single DS pipe, SIMD3) were split between two
// co-resident blocks running identical heavy traffic; the rotation A/B that
// would have tested this was spill-poisoned twice (256-VGPR wall at 2 blk/CU).
// At 1 blk/CU: DS traffic per CU halves, chain wave owns its SIMD, 512-VGPR
// budget removes the register wall entirely.
// Free bonus from 16 veh: MFMA cols were DUPLICATED (v8=n&7); with v8=n the
// same instruction count serves 16 vehicles, and the conv2 A-fragment becomes
// each lane's OWN packed pooled row -> the 8 chain ds_bpermutes are deleted.
// Schedule (R13): superstep = 2 model steps, ONE barrier; chain on wid3
// (swapped conv1 -> in-register conv2 -> O2 -> dense -> state); helpers:
// wid0 Jpart(2k+2,2k+3), wid1 j0(2k+4,2k+5)+flush, wid2 row0(2k+6,2k+7).
// LDS 115840B (<=160K; >64K static has HK/AITER precedent on gfx950).
// Spill tripwire: FETCH_SIZE ~5.4MB.

#define PAST 25
#define NTW_MAX 280

typedef __attribute__((ext_vector_type(8))) short bf16x8;
typedef __attribute__((ext_vector_type(4))) float f32x4;
typedef unsigned short u16x2 __attribute__((ext_vector_type(2)));
#define MFMA16 __builtin_amdgcn_mfma_f32_16x16x32_bf16

static __device__ __forceinline__ uint32_t f2bf(float f) {
  union { float f; uint32_t u; } x; x.f = f;
  return (x.u + 0x7FFFu + ((x.u >> 16) & 1u)) >> 16;
}
static __device__ __forceinline__ float bf2f(uint32_t b) {
  union { uint32_t u; float f; } x; x.u = b << 16; return x.f;
}
// one-instruction RNE pack of two f32 -> packed bf16x2 (low=lo, high=hi)
static __device__ __forceinline__ uint32_t pkbf(float lo, float hi) {
  uint32_t r;
  asm("v_cvt_pk_bf16_f32 %0, %1, %2" : "=v"(r) : "v"(lo), "v"(hi));
  return r;
}
static __device__ __forceinline__ f32x4 bcast4(float v) { f32x4 r = {v, v, v, v}; return r; }

static __device__ __forceinline__ uint32_t pkmax(uint32_t a, uint32_t b) {
#if __has_builtin(__builtin_elementwise_max)
  union U { uint32_t w; u16x2 v; } x, y; x.w = a; y.w = b;
  x.v = __builtin_elementwise_max(x.v, y.v);
  return x.w;
#else
  uint32_t al = a << 16, bl = b << 16;
  uint32_t lo = (al > bl ? al : bl) >> 16;
  uint32_t ah = a & 0xffff0000u, bh = b & 0xffff0000u;
  uint32_t hi = ah > bh ? ah : bh;
  return lo | hi;
#endif
}
static __device__ __forceinline__ uint4 maxq(uint4 a, uint4 b) {
  uint4 r; r.x = pkmax(a.x, b.x); r.y = pkmax(a.y, b.y);
  r.z = pkmax(a.z, b.z); r.w = pkmax(a.w, b.w); return r;
}
// wraps: valid for x < 63 (w21) / x < 51 (w17)
static __device__ __forceinline__ int w21(int x) { if (x >= 21) x -= 21; if (x >= 21) x -= 21; return x; }
static __device__ __forceinline__ int w17(int x) { if (x >= 17) x -= 17; if (x >= 17) x -= 17; return x; }
// sum across each 16-lane row via DPP rotate-accumulate (row_ror 1/2/4/8).
static __device__ __forceinline__ float rsum16(float x) {
  x += __builtin_bit_cast(float, __builtin_amdgcn_update_dpp(0, __builtin_bit_cast(int, x), 0x121, 0xf, 0xf, true));
  x += __builtin_bit_cast(float, __builtin_amdgcn_update_dpp(0, __builtin_bit_cast(int, x), 0x122, 0xf, 0xf, true));
  x += __builtin_bit_cast(float, __builtin_amdgcn_update_dpp(0, __builtin_bit_cast(int, x), 0x124, 0xf, 0xf, true));
  x += __builtin_bit_cast(float, __builtin_amdgcn_update_dpp(0, __builtin_bit_cast(int, x), 0x128, 0xf, 0xf, true));
  return x;
}

union FragU { bf16x8 v; uint16_t u[8]; uint4 q; };
struct RowD { f32x4 d0, d1; };   // swapped conv1 out: lane=veh (col n), regs=ch quad*4+r

// 4224 + 16384 + 8192 + 25600 + 45056 + 8192 + 4096 + 4096 = 115840 B
struct __align__(16) SMem {
  uint32_t Xcol[16][33][2];   // x-column ring (u&31)
  float    leadx[16][256];    // lead pos, idx = t, t in [0, ntw-26]
  uint16_t leady[16][256];    // f2bf(lead speed * 0.025)
  uint16_t P[25 * 16 * 32];   // conv1 pairs: ring 0..20 (g%21), R0 ring 21..24
  uint16_t O2[22 * 16 * 64];  // ring 0..16, J0 ring 17..20, 21 = j10 scratch
  float2 obuf[2][16][32];     // output dbuf (flushed every 32 steps)
  f32x4 JpartA[4][64];        // jp0..jp3 partial dense acc (hf=0), ring by t&3
  f32x4 JpartB[4][64];        // (hf=1)
};

__global__ __launch_bounds__(256, 1) void rnncf_kernel(
    const float* __restrict__ lead_states, const float* __restrict__ cur_states,
    const float* __restrict__ conv1_w, const float* __restrict__ conv1_b,
    const float* __restrict__ conv2_w, const float* __restrict__ conv2_b,
    const float* __restrict__ dense2_w, const float* __restrict__ dense2_b,
    const float* __restrict__ dense1_w, const float* __restrict__ dense1_b,
    float* __restrict__ out, int nt, int ntw) {
  __shared__ SMem sm;
  const int tid = threadIdx.x;
  const int lane = tid & 63;
  const int wid = tid >> 6;           // 0..3
  const int n = lane & 15;
  const int quad = lane >> 4;
  const int vbase = blockIdx.x * 16;

  // ---------------- phase 0: Xcol ring + lead preload + state ----------------
  for (int i = tid; i < 16 * PAST; i += 256) {
    int v = i & 15, u = i >> 4;
    const float2 l = *(const float2*)(lead_states + ((size_t)(vbase + v) * ntw + u) * 2);
    const float2 c = *(const float2*)(cur_states + ((size_t)(vbase + v) * PAST + u) * 2);
    float x0 = (l.x - c.x) * 0.005f;
    uint32_t w0 = pkbf(x0, c.y * 0.025f);
    sm.Xcol[v][u][0] = w0;
    sm.Xcol[v][u][1] = pkbf(l.y * 0.025f, x0 - bf2f(w0 & 0xffffu));
  }
#pragma unroll
  for (int v = 0; v < 16; ++v)
    for (int i = 25 + tid; i < ntw; i += 256) {
      const float2 l = *(const float2*)(lead_states + ((size_t)(vbase + v) * ntw + i) * 2);
      sm.leadx[v][i - 25] = l.x;
      sm.leady[v][i - 25] = (uint16_t)f2bf(l.y * 0.025f);
    }

  float pos_s = 0.f, spd_s = 0.f;
  if (wid == 3 && n < 4) {            // state lives on the chain wave; 16 veh
    int veh = quad * 4 + n;
    const float2 c = *(const float2*)(cur_states + ((size_t)(vbase + veh) * PAST + 24) * 2);
    pos_s = c.x * 0.005f; spd_s = c.y * 0.025f;
  }

  // ---------------- weight fragments ----------------
  FragU B1[2];
#pragma unroll
  for (int ct = 0; ct < 2; ++ct)
#pragma unroll
    for (int jj = 0; jj < 8; ++jj) {
      int k = quad * 8 + jj;
      int dw = k & 3, cig = (k >> 2) & 3;
      float w = 0.f;
      if (k < 16 && dw < 3) {
        int ci = (cig == 3) ? 0 : cig;
        w = conv1_w[(dw * 3 + ci) * 32 + ct * 16 + n];
      }
      B1[ct].u[jj] = (uint16_t)f2bf(w);
    }
  FragU B2[3][4];
#pragma unroll
  for (int dw = 0; dw < 3; ++dw)
#pragma unroll
    for (int ct = 0; ct < 4; ++ct)
#pragma unroll
      for (int jj = 0; jj < 8; ++jj) {
        int kap = quad * 8 + jj;
        int ci = (kap & 1) * 16 + (kap >> 1);
        B2[dw][ct].u[jj] = (uint16_t)f2bf(conv2_w[(dw * 32 + ci) * 64 + ct * 16 + n]);
      }
  FragU Bd[12];
#pragma unroll
  for (int kt = 0; kt < 12; ++kt)
#pragma unroll
    for (int jj = 0; jj < 8; ++jj) {
      int flat = kt * 32 + quad * 8 + jj;
      int jp = flat >> 6, kap = flat & 63;
      int co = (kap & 3) * 16 + (kap >> 2);
      Bd[kt].u[jj] = (uint16_t)f2bf((n < 10) ? dense2_w[(jp * 64 + co) * 10 + n] : 0.f);
    }
  f32x4 b1q0, b1q1;
#pragma unroll
  for (int r = 0; r < 4; ++r) {
    b1q0[r] = conv1_b[quad * 4 + r];
    b1q1[r] = conv1_b[16 + quad * 4 + r];
  }
  float b2v[4];
#pragma unroll
  for (int ct = 0; ct < 4; ++ct) b2v[ct] = conv2_b[ct * 16 + n];
  const float d2bv = (n < 10) ? dense2_b[n] : 0.f;
  const float wd1v = (n < 10) ? dense1_w[n] : 0.f;
  const float bd1v = dense1_b[0];

  // ---------------- helpers (16-veh indexing) ----------------
  auto pIdx = [&](int s, int veh, int ch) { return ((s * 16 + veh) * 4 + ch) * 8; };
  auto oIdx = [&](int s, int veh, int ch) { return ((s * 16 + veh) * 8 + ch) * 8; };

  auto build_x = [&](int c, int padL, int padR) -> FragU {
    int h = quad & 1, v8 = n;          // 16 distinct vehicle columns
    uint32_t d0 = padL ? 0u : sm.Xcol[v8][(c - 1) & 31][h];
    uint32_t d1 = sm.Xcol[v8][c & 31][h];
    uint32_t d2 = padR ? 0u : sm.Xcol[v8][(c + 1) & 31][h];
    FragU a;
    a.q.x = __builtin_amdgcn_perm(d1, d0, 0x05040100u);
    a.q.y = d2 & 0xffffu;
    a.q.z = __builtin_amdgcn_perm(d1, d0, 0x07060302u);
    a.q.w = d2 >> 16;
    return a;
  };

  auto conv1s_row = [&](int c, int padL, int padR) -> RowD {
    FragU a = build_x(c, padL, padR);
    RowD rd;
    rd.d0 = MFMA16(B1[0].v, a.v, b1q0, 0, 0, 0);
    rd.d1 = MFMA16(B1[1].v, a.v, b1q1, 0, 0, 0);
    return rd;
  };

  auto relumax4 = [&](const f32x4& a, const f32x4& b) -> f32x4 {
    f32x4 r;
#pragma unroll
    for (int i = 0; i < 4; ++i) r[i] = fmaxf(fmaxf(a[i], b[i]), 0.f);
    return r;
  };
  auto relu4 = [&](const f32x4& a) -> f32x4 {
    f32x4 r;
#pragma unroll
    for (int i = 0; i < 4; ++i) r[i] = fmaxf(a[i], 0.f);
    return r;
  };
  // packed pooled row: word r = (ct0 ch q4+r, ct1 ch q4+r) for veh n -- this
  // IS the conv2 A-fragment for lane (quad,n) (B2's permuted-K co-design),
  // so the chain consumes w11/w12 directly from registers (no transpose).
  auto pack4 = [&](const f32x4& p0, const f32x4& p1) -> uint4 {
    uint4 w;
    w.x = pkbf(p0[0], p1[0]); w.y = pkbf(p0[1], p1[1]);
    w.z = pkbf(p0[2], p1[2]); w.w = pkbf(p0[3], p1[3]);
    return w;
  };
  auto p_store = [&](const uint4& w, int ds) {
    *(uint4*)&sm.P[pIdx(ds, n, quad ^ (n & 3))] = w;   // all 16 veh
  };
  auto pool_store = [&](const RowD& A, const RowD& Bq, int ds) {
    p_store(pack4(relumax4(A.d0, Bq.d0), relumax4(A.d1, Bq.d1)), ds);
  };

  auto ld_P = [&](int s) -> FragU {
    FragU a; a.q = *(const uint4*)&sm.P[pIdx(s, n, quad ^ (n & 3))]; return a;
  };

  auto conv2_acc = [&](f32x4* acc, int slot, int dw) {
    FragU a = ld_P(slot);
#pragma unroll
    for (int ct = 0; ct < 4; ++ct) acc[ct] = MFMA16(a.v, B2[dw][ct].v, acc[ct], 0, 0, 0);
  };

  auto conv2_accf = [&](f32x4* acc, const FragU& a, int dw) {
#pragma unroll
    for (int ct = 0; ct < 4; ++ct) acc[ct] = MFMA16(a.v, B2[dw][ct].v, acc[ct], 0, 0, 0);
  };

  auto o2_write = [&](const f32x4* acc, int ds) {   // all 4 quads: 16 veh
#pragma unroll
    for (int r = 0; r < 4; ++r) {
      int veh = quad * 4 + r;
      float m0 = fmaxf(acc[0][r], 0.f), m1 = fmaxf(acc[1][r], 0.f);
      float m2 = fmaxf(acc[2][r], 0.f), m3 = fmaxf(acc[3][r], 0.f);
      uint2 w2; w2.x = pkbf(m0, m1); w2.y = pkbf(m2, m3);
      *(uint2*)&sm.O2[oIdx(ds, veh, (n >> 1) ^ (veh & 7)) + (n & 1) * 4] = w2;
    }
  };

  auto dense_jp = [&](int pa, int pb, int jp, f32x4& a0, f32x4& a1) {
#pragma unroll
    for (int hf = 0; hf < 2; ++hf) {
      uint4 qa = *(const uint4*)&sm.O2[oIdx(pa, n, (hf * 4 + quad) ^ (n & 7))];
      if (pb >= 0) {
        uint4 qb = *(const uint4*)&sm.O2[oIdx(pb, n, (hf * 4 + quad) ^ (n & 7))];
        qa = maxq(qa, qb);
      }
      FragU a; a.q = qa;
      if (hf == 0) a0 = MFMA16(a.v, Bd[jp * 2].v, a0, 0, 0, 0);
      else         a1 = MFMA16(a.v, Bd[jp * 2 + 1].v, a1, 0, 0, 0);
    }
  };

  auto dense_jp_pre = [&](int pa, const uint4* qpre, int jp, f32x4& a0, f32x4& a1) {
#pragma unroll
    for (int hf = 0; hf < 2; ++hf) {
      uint4 qa = *(const uint4*)&sm.O2[oIdx(pa, n, (hf * 4 + quad) ^ (n & 7))];
      if (qpre) qa = maxq(qa, qpre[hf]);
      FragU a; a.q = qa;
      if (hf == 0) a0 = MFMA16(a.v, Bd[jp * 2].v, a0, 0, 0, 0);
      else         a1 = MFMA16(a.v, Bd[jp * 2 + 1].v, a1, 0, 0, 0);
    }
  };

  auto flush_out = [&](int bi, int t0, int cnt) {   // 16 veh x 32 steps
    int vv = lane >> 2;
    int s0 = (lane & 3) * 8;
#pragma unroll
    for (int kk = 0; kk < 8; ++kk) {
      int s = s0 + kk;
      if (s < cnt) {
        float2 d = sm.obuf[bi][vv][s];
        *(float2*)(out + ((size_t)(vbase + vv) * nt + t0 + s) * 2) = d;
      }
    }
  };

  __syncthreads();

  // ---------------- phase 1: P ring init pairs g=2..21 ----------------
#pragma unroll
  for (int i = 0; i < 5; ++i) {
    int g = 2 + wid + 4 * i;
    RowD A = conv1s_row(g, 0, 0);
    RowD Bq = conv1s_row(g + 1, 0, 0);
    pool_store(A, Bq, g % 21);
  }
  __syncthreads();

  // ---------------- phase 2: O2 ring init a=2..17 ----------------
#pragma unroll
  for (int i = 0; i < 4; ++i) {
    int a = 2 + wid + 4 * i;
    f32x4 acc[4];
#pragma unroll
    for (int ct = 0; ct < 4; ++ct) acc[ct] = bcast4(b2v[ct]);
    conv2_acc(acc, a % 21, 0);
    conv2_acc(acc, (a + 2) % 21, 1);
    conv2_acc(acc, (a + 4) % 21, 2);
    o2_write(acc, a % 17);
  }
  __syncthreads();

  // ---------------- prologue ----------------
  RowD c1A = {};
  f32x4 accA[4] = {}, accB[4] = {};
  // ProA: R0(0)->P23, R0(1)->P24
  if (wid == 0) {
    RowD A = conv1s_row(0, 1, 0), Bq = conv1s_row(1, 0, 0);
    pool_store(A, Bq, 23);
  } else if (wid == 1) {
    RowD A = conv1s_row(1, 1, 0), Bq = conv1s_row(2, 0, 0);
    pool_store(A, Bq, 24);
  }
  __syncthreads();
  // ProB: j0(0)->O2[17], j0(1)->O2[18], R0(4)->P21, R0(5)->P22
  if (wid == 0) {
    f32x4 aj[4];
#pragma unroll
    for (int ct = 0; ct < 4; ++ct) aj[ct] = bcast4(b2v[ct]);
    conv2_acc(aj, 23, 0); conv2_acc(aj, 2, 1); conv2_acc(aj, 4, 2);
    o2_write(aj, 17);
  } else if (wid == 1) {
    f32x4 aj[4];
#pragma unroll
    for (int ct = 0; ct < 4; ++ct) aj[ct] = bcast4(b2v[ct]);
    conv2_acc(aj, 24, 0); conv2_acc(aj, 3, 1); conv2_acc(aj, 5, 2);
    o2_write(aj, 18);
  } else if (wid == 2) {
    RowD A = conv1s_row(4, 1, 0), Bq = conv1s_row(5, 0, 0);
    pool_store(A, Bq, 21);
  } else {
    RowD A = conv1s_row(5, 1, 0), Bq = conv1s_row(6, 0, 0);
    pool_store(A, Bq, 22);
  }
  __syncthreads();
  // ProC: Jpart(0)->Jp[0], Jpart(1)->Jp[1], R0(2)->P23, R0(3)->P24
  if (wid == 0) {
    f32x4 a0 = bcast4(d2bv), a1 = bcast4(0.f);
    dense_jp(17, 2, 0, a0, a1);
    dense_jp(4, 6, 1, a0, a1);
    dense_jp(8, 10, 2, a0, a1);
    dense_jp(12, 14, 3, a0, a1);
    sm.JpartA[0][lane] = a0; sm.JpartB[0][lane] = a1;
  } else if (wid == 1) {
    f32x4 a0 = bcast4(d2bv), a1 = bcast4(0.f);
    dense_jp(18, 3, 0, a0, a1);
    dense_jp(5, 7, 1, a0, a1);
    dense_jp(9, 11, 2, a0, a1);
    dense_jp(13, 15, 3, a0, a1);
    sm.JpartA[1][lane] = a0; sm.JpartB[1][lane] = a1;
  } else if (wid == 2) {
    RowD A = conv1s_row(2, 1, 0), Bq = conv1s_row(3, 0, 0);
    pool_store(A, Bq, 23);
  } else {
    RowD A = conv1s_row(3, 1, 0), Bq = conv1s_row(4, 0, 0);
    pool_store(A, Bq, 24);
  }
  __syncthreads();
  // ProD: j0(2)->O2[19], j0(3)->O2[20], chain accs + c1A
  if (wid == 0) {
    f32x4 aj[4];
#pragma unroll
    for (int ct = 0; ct < 4; ++ct) aj[ct] = bcast4(b2v[ct]);
    conv2_acc(aj, 23, 0); conv2_acc(aj, 4, 1); conv2_acc(aj, 6, 2);
    o2_write(aj, 19);
  } else if (wid == 1) {
    f32x4 aj[4];
#pragma unroll
    for (int ct = 0; ct < 4; ++ct) aj[ct] = bcast4(b2v[ct]);
    conv2_acc(aj, 24, 0); conv2_acc(aj, 5, 1); conv2_acc(aj, 7, 2);
    o2_write(aj, 20);
  } else if (wid == 3) {
#pragma unroll
    for (int ct = 0; ct < 4; ++ct) accA[ct] = bcast4(b2v[ct]);
    conv2_acc(accA, 18, 0);         // j9(0) dw0 (pair g=18)
    conv2_acc(accA, 20, 1);         // j9(0) dw1 (pair g=20)
#pragma unroll
    for (int ct = 0; ct < 4; ++ct) accB[ct] = bcast4(b2v[ct]);
    conv2_acc(accB, 20, 0);         // j10(0) dw0
    c1A = conv1s_row(22, 0, 0);
  }
  __syncthreads();

  if (wid == 3) __builtin_amdgcn_s_setprio(2);

  // ---------------- supersteps: 2 model steps per barrier ----------------
  int tmA21 = 0, tmA17 = 0;     // (2k)%21, (2k)%17
  const int nsup = nt >> 1;     // nt is even (256)
  for (int k = 0; k < nsup; ++k) {
    if (wid == 3) {
#pragma unroll
      for (int d = 0; d < 2; ++d) {
        const int t = 2 * k + d;
        const int sP22 = w21(tmA21 + d + 22);
        const int sO16 = w17(tmA17 + d + 16);
        const int sO18 = w17(tmA17 + d + 18);
        const int sP18n = w21(tmA21 + d + 19);   // (t+1+18)%21
        const int sP20n = w21(tmA21 + d + 21);   // (t+1+20)%21
        // early off-chain loads
        f32x4 jpA = sm.JpartA[t & 3][lane];
        f32x4 jpB = sm.JpartB[t & 3][lane];
        uint4 qj8[2];
#pragma unroll
        for (int hf = 0; hf < 2; ++hf)
          qj8[hf] = *(const uint4*)&sm.O2[oIdx(sO16, n, (hf * 4 + quad) ^ (n & 7))];
        FragU fA18 = ld_P(sP18n);
        FragU fA20 = ld_P(sP20n);
        // fresh conv1 (swapped; fragments stay in registers)
        RowD Bq = conv1s_row(t + 23, 0, 0);
        RowD Sg = conv1s_row(t + 24, 0, 1);
        uint4 w11 = pack4(relumax4(c1A.d0, Bq.d0), relumax4(c1A.d1, Bq.d1));
        uint4 w12 = pack4(relu4(Sg.d0), relu4(Sg.d1));
        p_store(w11, sP22);
        c1A = Bq;
        FragU f11; f11.q = w11;                 // identity: own lane's frag
        FragU f12; f12.q = w12;
        conv2_accf(accA, f11, 2);               // j9 complete
        conv2_accf(accB, f11, 1);
        conv2_accf(accB, f12, 2);               // j10 complete
        o2_write(accA, sO18);                   // j9 -> ring
        o2_write(accB, 21);                     // j10 -> scratch 21
        // dense + reduce + state (DS in-order covers write->read)
        f32x4 acc2 = bcast4(0.f), acc3 = bcast4(0.f);
        f32x4 acc4 = bcast4(0.f), acc5 = bcast4(0.f);
        dense_jp_pre(sO18, qj8, 4, acc2, acc3);
        dense_jp_pre(21, (const uint4*)nullptr, 5, acc4, acc5);
        float s0 = fmaxf(jpA[0] + jpB[0] + acc2[0] + acc3[0] + acc4[0] + acc5[0], 0.f) * wd1v;
        float s1 = fmaxf(jpA[1] + jpB[1] + acc2[1] + acc3[1] + acc4[1] + acc5[1], 0.f) * wd1v;
        float s2 = fmaxf(jpA[2] + jpB[2] + acc2[2] + acc3[2] + acc4[2] + acc5[2], 0.f) * wd1v;
        float s3 = fmaxf(jpA[3] + jpB[3] + acc2[3] + acc3[3] + acc4[3] + acc5[3], 0.f) * wd1v;
        s0 = rsum16(s0); s1 = rsum16(s1); s2 = rsum16(s2); s3 = rsum16(s3);
        if (n < 4) {                            // all 4 quads: 16 veh
          int veh = quad * 4 + n;
          float sv = (n == 0) ? s0 : (n == 1) ? s1 : (n == 2) ? s2 : s3;
          float accv = 10.f * (sv + bd1v) - 6.f;
          float np_s = pos_s + 0.02f * spd_s;
          float nsp = spd_s * 40.f + 0.1f * accv;
          pos_s = np_s; spd_s = nsp * 0.025f;
          float2 o2v; o2v.x = np_s * 200.f; o2v.y = nsp;
          sm.obuf[(t >> 5) & 1][veh][t & 31] = o2v;
          int li = t; if (li > ntw - 26) li = ntw - 26;
          float lnx = sm.leadx[veh][li];
          float lny = bf2f(sm.leady[veh][li]);
          float x0 = lnx * 0.005f - np_s;
          uint32_t wlo = pkbf(x0, spd_s);
          sm.Xcol[veh][(t + PAST) & 31][0] = wlo;
          sm.Xcol[veh][(t + PAST) & 31][1] = pkbf(lny, x0 - bf2f(wlo & 0xffffu));
        }
        // next-step partial accs (register MFMA tail)
#pragma unroll
        for (int ct = 0; ct < 4; ++ct) accA[ct] = bcast4(b2v[ct]);
        conv2_accf(accA, fA18, 0);
        conv2_accf(accA, fA20, 1);
#pragma unroll
        for (int ct = 0; ct < 4; ++ct) accB[ct] = bcast4(b2v[ct]);
        conv2_accf(accB, fA20, 0);
      }
    } else if (wid == 0) {
      // Jpart(2k+2), Jpart(2k+3)
#pragma unroll
      for (int e = 0; e < 2; ++e) {
        const int tau = 2 * k + 2 + e;
        f32x4 a0 = bcast4(d2bv), a1 = bcast4(0.f);
        dense_jp(17 + (tau & 3), w17(tmA17 + 4 + e), 0, a0, a1);     // jp0 = max(j0, j1)
        dense_jp(w17(tmA17 + 6 + e), w17(tmA17 + 8 + e), 1, a0, a1);
        dense_jp(w17(tmA17 + 10 + e), w17(tmA17 + 12 + e), 2, a0, a1);
        dense_jp(w17(tmA17 + 14 + e), w17(tmA17 + 16 + e), 3, a0, a1);
        sm.JpartA[tau & 3][lane] = a0;
        sm.JpartB[tau & 3][lane] = a1;
      }
    } else if (wid == 1) {
      // obuf flush (32-step blocks) + j0(2k+4), j0(2k+5)
      if ((k & 15) == 0 && k > 0) {
        int t0 = 2 * k - 32;
        flush_out((t0 >> 5) & 1, t0, 32);
      }
#pragma unroll
      for (int e = 0; e < 2; ++e) {
        const int tau = 2 * k + 4 + e;
        f32x4 aj[4];
#pragma unroll
        for (int ct = 0; ct < 4; ++ct) aj[ct] = bcast4(b2v[ct]);
        conv2_acc(aj, 21 + (tau & 3), 0);                 // R0(tau)
        conv2_acc(aj, w21(tmA21 + 6 + e), 1);             // pair tau+2
        conv2_acc(aj, w21(tmA21 + 8 + e), 2);             // pair tau+4
        o2_write(aj, 17 + (tau & 3));                     // J0[tau&3]
      }
    } else {
      // row0(2k+6), row0(2k+7)
#pragma unroll
      for (int f = 0; f < 2; ++f) {
        const int tau = 2 * k + 6 + f;
        RowD A = conv1s_row(tau, 1, 0);
        RowD Bq = conv1s_row(tau + 1, 0, 0);
        pool_store(A, Bq, 21 + (tau & 3));
      }
    }
    __syncthreads();
    tmA21 = w21(tmA21 + 2);
    tmA17 = w17(tmA17 + 2);
  }

  // final output flush (steps [nt-32, nt-1])
  if (wid == 1) {
    int t0 = (nt - 1) & ~31;
    flush_out((t0 >> 5) & 1, t0, nt - t0);
  }
}

extern "C" void kernel_launch(void* const* d_in, const int* in_sizes, int n_in,
                              void* d_out, int out_size, void* d_ws, size_t ws_size,
                              hipStream_t stream) {
  const float* lead = (const float*)d_in[0];
  const float* cur  = (const float*)d_in[1];
  // d_in[2] = mask (unused by reference)
  const float* c1w = (const float*)d_in[3];
  const float* c1b = (const float*)d_in[4];
  const float* c2w = (const float*)d_in[5];
  const float* c2b = (const float*)d_in[6];
  const float* d2w = (const float*)d_in[7];
  const float* d2b = (const float*)d_in[8];
  const float* d1w = (const float*)d_in[9];
  const float* d1b = (const float*)d_in[10];
  float* out = (float*)d_out;

  int nveh = in_sizes[1] / (PAST * 2);   // 4096
  int ntw  = in_sizes[2] / nveh;         // nt + PAST - 1 (<= NTW_MAX)
  int nt   = ntw - PAST + 1;             // 256 (even)
  int nblocks = nveh / 16;               // 256 = one per CU

  rnncf_kernel<<<nblocks, 256, 0, stream>>>(lead, cur, c1w, c1b, c2w, c2b,
                                            d2w, d2b, d1w, d1b, out, nt, ntw);
}

// Round 11
// 351.672 us; speedup vs baseline: 1.3310x; 1.1085x over previous
//
#include <hip/hip_runtime.h>
#include <stdint.h>

// RNN car-following, 256 sequential steps x 4096 vehicles.
// Round-15: chain-wave diet. R14 established the step time IS the chain
// wave's serial issue+latency (~2900cy/step; 1blk/CU vs 2blk/CU moved it
// only 3%). Three chain-local cuts, enabled by the 512-VGPR / 160KB-LDS
// headroom of 1 block/CU:
//  1. j9/j10 PARTIAL accs (dw0/dw1 taps, all >=4-step-old P pairs) move to
//     wid2, stored in 4-deep LDS rings JA2/JB2 (+32KB, total 148.6KB).
//     Chain: 12 MFMA + 2 frag loads + bias inits -> 8 early ds_read_b128.
//  2. lead[] read hoisted to step start (it's ON the loop-carried path:
//     lead -> x0 -> Xcol write -> next conv1). Spilled at the old 128-VGPR
//     cap (R9); free at 152/512.
//  3. shared-column conv1: Bq/Sg overlap -> 3 Xcol reads instead of 6.
// Schedule (R13/R14): superstep = 2 steps, ONE barrier; chain on wid3;
// helpers: wid0 Jpart(2k+2,2k+3), wid1 j0(2k+4,2k+5)+flush,
// wid2 j9/j10-partials(2k+2,2k+3) + row0(2k+6,2k+7).
// Spill tripwire: FETCH_SIZE ~5.4MB.

#define PAST 25
#define NTW_MAX 280

typedef __attribute__((ext_vector_type(8))) short bf16x8;
typedef __attribute__((ext_vector_type(4))) float f32x4;
typedef unsigned short u16x2 __attribute__((ext_vector_type(2)));
#define MFMA16 __builtin_amdgcn_mfma_f32_16x16x32_bf16

static __device__ __forceinline__ uint32_t f2bf(float f) {
  union { float f; uint32_t u; } x; x.f = f;
  return (x.u + 0x7FFFu + ((x.u >> 16) & 1u)) >> 16;
}
static __device__ __forceinline__ float bf2f(uint32_t b) {
  union { uint32_t u; float f; } x; x.u = b << 16; return x.f;
}
// one-instruction RNE pack of two f32 -> packed bf16x2 (low=lo, high=hi)
static __device__ __forceinline__ uint32_t pkbf(float lo, float hi) {
  uint32_t r;
  asm("v_cvt_pk_bf16_f32 %0, %1, %2" : "=v"(r) : "v"(lo), "v"(hi));
  return r;
}
static __device__ __forceinline__ f32x4 bcast4(float v) { f32x4 r = {v, v, v, v}; return r; }

static __device__ __forceinline__ uint32_t pkmax(uint32_t a, uint32_t b) {
#if __has_builtin(__builtin_elementwise_max)
  union U { uint32_t w; u16x2 v; } x, y; x.w = a; y.w = b;
  x.v = __builtin_elementwise_max(x.v, y.v);
  return x.w;
#else
  uint32_t al = a << 16, bl = b << 16;
  uint32_t lo = (al > bl ? al : bl) >> 16;
  uint32_t ah = a & 0xffff0000u, bh = b & 0xffff0000u;
  uint32_t hi = ah > bh ? ah : bh;
  return lo | hi;
#endif
}
static __device__ __forceinline__ uint4 maxq(uint4 a, uint4 b) {
  uint4 r; r.x = pkmax(a.x, b.x); r.y = pkmax(a.y, b.y);
  r.z = pkmax(a.z, b.z); r.w = pkmax(a.w, b.w); return r;
}
// wraps: valid for x < 63 (w21) / x < 51 (w17)
static __device__ __forceinline__ int w21(int x) { if (x >= 21) x -= 21; if (x >= 21) x -= 21; return x; }
static __device__ __forceinline__ int w17(int x) { if (x >= 17) x -= 17; if (x >= 17) x -= 17; return x; }
// sum across each 16-lane row via DPP rotate-accumulate (row_ror 1/2/4/8).
static __device__ __forceinline__ float rsum16(float x) {
  x += __builtin_bit_cast(float, __builtin_amdgcn_update_dpp(0, __builtin_bit_cast(int, x), 0x121, 0xf, 0xf, true));
  x += __builtin_bit_cast(float, __builtin_amdgcn_update_dpp(0, __builtin_bit_cast(int, x), 0x122, 0xf, 0xf, true));
  x += __builtin_bit_cast(float, __builtin_amdgcn_update_dpp(0, __builtin_bit_cast(int, x), 0x124, 0xf, 0xf, true));
  x += __builtin_bit_cast(float, __builtin_amdgcn_update_dpp(0, __builtin_bit_cast(int, x), 0x128, 0xf, 0xf, true));
  return x;
}

union FragU { bf16x8 v; uint16_t u[8]; uint4 q; };
struct RowD { f32x4 d0, d1; };   // swapped conv1 out: lane=veh (col n), regs=ch quad*4+r

// 4224 + 16384 + 8192 + 25600 + 45056 + 8192 + 4096 + 4096 + 16384 + 16384 = 148608 B
struct __align__(16) SMem {
  uint32_t Xcol[16][33][2];   // x-column ring (u&31)
  float    leadx[16][256];    // lead pos, idx = t, t in [0, ntw-26]
  uint16_t leady[16][256];    // f2bf(lead speed * 0.025)
  uint16_t P[25 * 16 * 32];   // conv1 pairs: ring 0..20 (g%21), R0 ring 21..24
  uint16_t O2[22 * 16 * 64];  // ring 0..16, J0 ring 17..20, 21 = j10 scratch
  float2 obuf[2][16][32];     // output dbuf (flushed every 32 steps)
  f32x4 JpartA[4][64];        // jp0..jp3 partial dense acc (hf=0), ring by t&3
  f32x4 JpartB[4][64];        // (hf=1)
  f32x4 JA2[4][4][64];        // j9 partial (bias+dw0+dw1), ring by t&3, [ct][lane]
  f32x4 JB2[4][4][64];        // j10 partial (bias+dw0)
};

__global__ __launch_bounds__(256, 1) void rnncf_kernel(
    const float* __restrict__ lead_states, const float* __restrict__ cur_states,
    const float* __restrict__ conv1_w, const float* __restrict__ conv1_b,
    const float* __restrict__ conv2_w, const float* __restrict__ conv2_b,
    const float* __restrict__ dense2_w, const float* __restrict__ dense2_b,
    const float* __restrict__ dense1_w, const float* __restrict__ dense1_b,
    float* __restrict__ out, int nt, int ntw) {
  __shared__ SMem sm;
  const int tid = threadIdx.x;
  const int lane = tid & 63;
  const int wid = tid >> 6;           // 0..3
  const int n = lane & 15;
  const int quad = lane >> 4;
  const int vbase = blockIdx.x * 16;

  // ---------------- phase 0: Xcol ring + lead preload + state ----------------
  for (int i = tid; i < 16 * PAST; i += 256) {
    int v = i & 15, u = i >> 4;
    const float2 l = *(const float2*)(lead_states + ((size_t)(vbase + v) * ntw + u) * 2);
    const float2 c = *(const float2*)(cur_states + ((size_t)(vbase + v) * PAST + u) * 2);
    float x0 = (l.x - c.x) * 0.005f;
    uint32_t w0 = pkbf(x0, c.y * 0.025f);
    sm.Xcol[v][u][0] = w0;
    sm.Xcol[v][u][1] = pkbf(l.y * 0.025f, x0 - bf2f(w0 & 0xffffu));
  }
#pragma unroll
  for (int v = 0; v < 16; ++v)
    for (int i = 25 + tid; i < ntw; i += 256) {
      const float2 l = *(const float2*)(lead_states + ((size_t)(vbase + v) * ntw + i) * 2);
      sm.leadx[v][i - 25] = l.x;
      sm.leady[v][i - 25] = (uint16_t)f2bf(l.y * 0.025f);
    }

  float pos_s = 0.f, spd_s = 0.f;
  if (wid == 3 && n < 4) {            // state lives on the chain wave; 16 veh
    int veh = quad * 4 + n;
    const float2 c = *(const float2*)(cur_states + ((size_t)(vbase + veh) * PAST + 24) * 2);
    pos_s = c.x * 0.005f; spd_s = c.y * 0.025f;
  }

  // ---------------- weight fragments ----------------
  FragU B1[2];
#pragma unroll
  for (int ct = 0; ct < 2; ++ct)
#pragma unroll
    for (int jj = 0; jj < 8; ++jj) {
      int k = quad * 8 + jj;
      int dw = k & 3, cig = (k >> 2) & 3;
      float w = 0.f;
      if (k < 16 && dw < 3) {
        int ci = (cig == 3) ? 0 : cig;
        w = conv1_w[(dw * 3 + ci) * 32 + ct * 16 + n];
      }
      B1[ct].u[jj] = (uint16_t)f2bf(w);
    }
  FragU B2[3][4];
#pragma unroll
  for (int dw = 0; dw < 3; ++dw)
#pragma unroll
    for (int ct = 0; ct < 4; ++ct)
#pragma unroll
      for (int jj = 0; jj < 8; ++jj) {
        int kap = quad * 8 + jj;
        int ci = (kap & 1) * 16 + (kap >> 1);
        B2[dw][ct].u[jj] = (uint16_t)f2bf(conv2_w[(dw * 32 + ci) * 64 + ct * 16 + n]);
      }
  FragU Bd[12];
#pragma unroll
  for (int kt = 0; kt < 12; ++kt)
#pragma unroll
    for (int jj = 0; jj < 8; ++jj) {
      int flat = kt * 32 + quad * 8 + jj;
      int jp = flat >> 6, kap = flat & 63;
      int co = (kap & 3) * 16 + (kap >> 2);
      Bd[kt].u[jj] = (uint16_t)f2bf((n < 10) ? dense2_w[(jp * 64 + co) * 10 + n] : 0.f);
    }
  f32x4 b1q0, b1q1;
#pragma unroll
  for (int r = 0; r < 4; ++r) {
    b1q0[r] = conv1_b[quad * 4 + r];
    b1q1[r] = conv1_b[16 + quad * 4 + r];
  }
  float b2v[4];
#pragma unroll
  for (int ct = 0; ct < 4; ++ct) b2v[ct] = conv2_b[ct * 16 + n];
  const float d2bv = (n < 10) ? dense2_b[n] : 0.f;
  const float wd1v = (n < 10) ? dense1_w[n] : 0.f;
  const float bd1v = dense1_b[0];

  // ---------------- helpers (16-veh indexing) ----------------
  auto pIdx = [&](int s, int veh, int ch) { return ((s * 16 + veh) * 4 + ch) * 8; };
  auto oIdx = [&](int s, int veh, int ch) { return ((s * 16 + veh) * 8 + ch) * 8; };

  auto build_x = [&](int c, int padL, int padR) -> FragU {
    int h = quad & 1, v8 = n;
    uint32_t d0 = padL ? 0u : sm.Xcol[v8][(c - 1) & 31][h];
    uint32_t d1 = sm.Xcol[v8][c & 31][h];
    uint32_t d2 = padR ? 0u : sm.Xcol[v8][(c + 1) & 31][h];
    FragU a;
    a.q.x = __builtin_amdgcn_perm(d1, d0, 0x05040100u);
    a.q.y = d2 & 0xffffu;
    a.q.z = __builtin_amdgcn_perm(d1, d0, 0x07060302u);
    a.q.w = d2 >> 16;
    return a;
  };

  auto conv1s_row = [&](int c, int padL, int padR) -> RowD {
    FragU a = build_x(c, padL, padR);
    RowD rd;
    rd.d0 = MFMA16(B1[0].v, a.v, b1q0, 0, 0, 0);
    rd.d1 = MFMA16(B1[1].v, a.v, b1q1, 0, 0, 0);
    return rd;
  };

  auto relumax4 = [&](const f32x4& a, const f32x4& b) -> f32x4 {
    f32x4 r;
#pragma unroll
    for (int i = 0; i < 4; ++i) r[i] = fmaxf(fmaxf(a[i], b[i]), 0.f);
    return r;
  };
  auto relu4 = [&](const f32x4& a) -> f32x4 {
    f32x4 r;
#pragma unroll
    for (int i = 0; i < 4; ++i) r[i] = fmaxf(a[i], 0.f);
    return r;
  };
  auto pack4 = [&](const f32x4& p0, const f32x4& p1) -> uint4 {
    uint4 w;
    w.x = pkbf(p0[0], p1[0]); w.y = pkbf(p0[1], p1[1]);
    w.z = pkbf(p0[2], p1[2]); w.w = pkbf(p0[3], p1[3]);
    return w;
  };
  auto p_store = [&](const uint4& w, int ds) {
    *(uint4*)&sm.P[pIdx(ds, n, quad ^ (n & 3))] = w;
  };
  auto pool_store = [&](const RowD& A, const RowD& Bq, int ds) {
    p_store(pack4(relumax4(A.d0, Bq.d0), relumax4(A.d1, Bq.d1)), ds);
  };

  auto ld_P = [&](int s) -> FragU {
    FragU a; a.q = *(const uint4*)&sm.P[pIdx(s, n, quad ^ (n & 3))]; return a;
  };

  auto conv2_acc = [&](f32x4* acc, int slot, int dw) {
    FragU a = ld_P(slot);
#pragma unroll
    for (int ct = 0; ct < 4; ++ct) acc[ct] = MFMA16(a.v, B2[dw][ct].v, acc[ct], 0, 0, 0);
  };

  auto conv2_accf = [&](f32x4* acc, const FragU& a, int dw) {
#pragma unroll
    for (int ct = 0; ct < 4; ++ct) acc[ct] = MFMA16(a.v, B2[dw][ct].v, acc[ct], 0, 0, 0);
  };

  auto o2_write = [&](const f32x4* acc, int ds) {
#pragma unroll
    for (int r = 0; r < 4; ++r) {
      int veh = quad * 4 + r;
      float m0 = fmaxf(acc[0][r], 0.f), m1 = fmaxf(acc[1][r], 0.f);
      float m2 = fmaxf(acc[2][r], 0.f), m3 = fmaxf(acc[3][r], 0.f);
      uint2 w2; w2.x = pkbf(m0, m1); w2.y = pkbf(m2, m3);
      *(uint2*)&sm.O2[oIdx(ds, veh, (n >> 1) ^ (veh & 7)) + (n & 1) * 4] = w2;
    }
  };

  auto dense_jp = [&](int pa, int pb, int jp, f32x4& a0, f32x4& a1) {
#pragma unroll
    for (int hf = 0; hf < 2; ++hf) {
      uint4 qa = *(const uint4*)&sm.O2[oIdx(pa, n, (hf * 4 + quad) ^ (n & 7))];
      if (pb >= 0) {
        uint4 qb = *(const uint4*)&sm.O2[oIdx(pb, n, (hf * 4 + quad) ^ (n & 7))];
        qa = maxq(qa, qb);
      }
      FragU a; a.q = qa;
      if (hf == 0) a0 = MFMA16(a.v, Bd[jp * 2].v, a0, 0, 0, 0);
      else         a1 = MFMA16(a.v, Bd[jp * 2 + 1].v, a1, 0, 0, 0);
    }
  };

  auto dense_jp_pre = [&](int pa, const uint4* qpre, int jp, f32x4& a0, f32x4& a1) {
#pragma unroll
    for (int hf = 0; hf < 2; ++hf) {
      uint4 qa = *(const uint4*)&sm.O2[oIdx(pa, n, (hf * 4 + quad) ^ (n & 7))];
      if (qpre) qa = maxq(qa, qpre[hf]);
      FragU a; a.q = qa;
      if (hf == 0) a0 = MFMA16(a.v, Bd[jp * 2].v, a0, 0, 0, 0);
      else         a1 = MFMA16(a.v, Bd[jp * 2 + 1].v, a1, 0, 0, 0);
    }
  };

  auto flush_out = [&](int bi, int t0, int cnt) {
    int vv = lane >> 2;
    int s0 = (lane & 3) * 8;
#pragma unroll
    for (int kk = 0; kk < 8; ++kk) {
      int s = s0 + kk;
      if (s < cnt) {
        float2 d = sm.obuf[bi][vv][s];
        *(float2*)(out + ((size_t)(vbase + vv) * nt + t0 + s) * 2) = d;
      }
    }
  };

  // j9/j10 partial accs (dw0/dw1: all >=4-step-old P pairs) -> JA2/JB2 rings
  auto j9j10_partial = [&](int ring, int pA, int pB) {
    f32x4 aA[4], aB[4];
#pragma unroll
    for (int ct = 0; ct < 4; ++ct) { aA[ct] = bcast4(b2v[ct]); aB[ct] = bcast4(b2v[ct]); }
    conv2_acc(aA, pA, 0);
    conv2_acc(aA, pB, 1);
    conv2_acc(aB, pB, 0);
#pragma unroll
    for (int ct = 0; ct < 4; ++ct) {
      sm.JA2[ring][ct][lane] = aA[ct];
      sm.JB2[ring][ct][lane] = aB[ct];
    }
  };

  __syncthreads();

  // ---------------- phase 1: P ring init pairs g=2..21 ----------------
#pragma unroll
  for (int i = 0; i < 5; ++i) {
    int g = 2 + wid + 4 * i;
    RowD A = conv1s_row(g, 0, 0);
    RowD Bq = conv1s_row(g + 1, 0, 0);
    pool_store(A, Bq, g % 21);
  }
  __syncthreads();

  // ---------------- phase 2: O2 ring init a=2..17 ----------------
#pragma unroll
  for (int i = 0; i < 4; ++i) {
    int a = 2 + wid + 4 * i;
    f32x4 acc[4];
#pragma unroll
    for (int ct = 0; ct < 4; ++ct) acc[ct] = bcast4(b2v[ct]);
    conv2_acc(acc, a % 21, 0);
    conv2_acc(acc, (a + 2) % 21, 1);
    conv2_acc(acc, (a + 4) % 21, 2);
    o2_write(acc, a % 17);
  }
  __syncthreads();

  // ---------------- prologue ----------------
  RowD c1A = {};
  // ProA: R0(0)->P23, R0(1)->P24
  if (wid == 0) {
    RowD A = conv1s_row(0, 1, 0), Bq = conv1s_row(1, 0, 0);
    pool_store(A, Bq, 23);
  } else if (wid == 1) {
    RowD A = conv1s_row(1, 1, 0), Bq = conv1s_row(2, 0, 0);
    pool_store(A, Bq, 24);
  }
  __syncthreads();
  // ProB: j0(0)->O2[17], j0(1)->O2[18], R0(4)->P21, R0(5)->P22
  if (wid == 0) {
    f32x4 aj[4];
#pragma unroll
    for (int ct = 0; ct < 4; ++ct) aj[ct] = bcast4(b2v[ct]);
    conv2_acc(aj, 23, 0); conv2_acc(aj, 2, 1); conv2_acc(aj, 4, 2);
    o2_write(aj, 17);
  } else if (wid == 1) {
    f32x4 aj[4];
#pragma unroll
    for (int ct = 0; ct < 4; ++ct) aj[ct] = bcast4(b2v[ct]);
    conv2_acc(aj, 24, 0); conv2_acc(aj, 3, 1); conv2_acc(aj, 5, 2);
    o2_write(aj, 18);
  } else if (wid == 2) {
    RowD A = conv1s_row(4, 1, 0), Bq = conv1s_row(5, 0, 0);
    pool_store(A, Bq, 21);
  } else {
    RowD A = conv1s_row(5, 1, 0), Bq = conv1s_row(6, 0, 0);
    pool_store(A, Bq, 22);
  }
  __syncthreads();
  // ProC: Jpart(0)->Jp[0], Jpart(1)->Jp[1], R0(2)->P23, R0(3)->P24
  if (wid == 0) {
    f32x4 a0 = bcast4(d2bv), a1 = bcast4(0.f);
    dense_jp(17, 2, 0, a0, a1);
    dense_jp(4, 6, 1, a0, a1);
    dense_jp(8, 10, 2, a0, a1);
    dense_jp(12, 14, 3, a0, a1);
    sm.JpartA[0][lane] = a0; sm.JpartB[0][lane] = a1;
  } else if (wid == 1) {
    f32x4 a0 = bcast4(d2bv), a1 = bcast4(0.f);
    dense_jp(18, 3, 0, a0, a1);
    dense_jp(5, 7, 1, a0, a1);
    dense_jp(9, 11, 2, a0, a1);
    dense_jp(13, 15, 3, a0, a1);
    sm.JpartA[1][lane] = a0; sm.JpartB[1][lane] = a1;
  } else if (wid == 2) {
    RowD A = conv1s_row(2, 1, 0), Bq = conv1s_row(3, 0, 0);
    pool_store(A, Bq, 23);
  } else {
    RowD A = conv1s_row(3, 1, 0), Bq = conv1s_row(4, 0, 0);
    pool_store(A, Bq, 24);
  }
  __syncthreads();
  // ProD: j0(2)->O2[19], j0(3)->O2[20], j9/j10 partials(0,1), chain c1A
  if (wid == 0) {
    f32x4 aj[4];
#pragma unroll
    for (int ct = 0; ct < 4; ++ct) aj[ct] = bcast4(b2v[ct]);
    conv2_acc(aj, 23, 0); conv2_acc(aj, 4, 1); conv2_acc(aj, 6, 2);
    o2_write(aj, 19);
  } else if (wid == 1) {
    f32x4 aj[4];
#pragma unroll
    for (int ct = 0; ct < 4; ++ct) aj[ct] = bcast4(b2v[ct]);
    conv2_acc(aj, 24, 0); conv2_acc(aj, 5, 1); conv2_acc(aj, 7, 2);
    o2_write(aj, 20);
  } else if (wid == 2) {
    j9j10_partial(0, 18, 20);          // tau=0: pairs 18, 20
    j9j10_partial(1, 19, 0);           // tau=1: pairs 19, (21)%21=0
  } else {
    c1A = conv1s_row(22, 0, 0);
  }
  __syncthreads();

  if (wid == 3) __builtin_amdgcn_s_setprio(2);

  // ---------------- supersteps: 2 model steps per barrier ----------------
  int tmA21 = 0, tmA17 = 0;     // (2k)%21, (2k)%17
  const int nsup = nt >> 1;     // nt is even (256)
  for (int k = 0; k < nsup; ++k) {
    if (wid == 3) {
#pragma unroll
      for (int d = 0; d < 2; ++d) {
        const int t = 2 * k + d;
        const int sP22 = w21(tmA21 + d + 22);
        const int sO16 = w17(tmA17 + d + 16);
        const int sO18 = w17(tmA17 + d + 18);
        // ---- early off-chain loads (latency hidden under conv1) ----
        f32x4 jpA = sm.JpartA[t & 3][lane];
        f32x4 jpB = sm.JpartB[t & 3][lane];
        f32x4 pA[4], pB[4];                     // j9/j10 partials from wid2
#pragma unroll
        for (int ct = 0; ct < 4; ++ct) {
          pA[ct] = sm.JA2[t & 3][ct][lane];
          pB[ct] = sm.JB2[t & 3][ct][lane];
        }
        uint4 qj8[2];
#pragma unroll
        for (int hf = 0; hf < 2; ++hf)
          qj8[hf] = *(const uint4*)&sm.O2[oIdx(sO16, n, (hf * 4 + quad) ^ (n & 7))];
        // lead prefetch (ON the loop-carried path; hoisted, reg headroom ok)
        int li = t; if (li > ntw - 26) li = ntw - 26;
        float lnx = 0.f, lny = 0.f;
        if (n < 4) {
          int veh = quad * 4 + n;
          lnx = sm.leadx[veh][li];
          lny = bf2f(sm.leady[veh][li]);
        }
        // ---- fresh conv1 (shared columns t+22..t+24; Sg is padR) ----
        {
          int h = quad & 1;
          uint32_t d22 = sm.Xcol[n][(t + 22) & 31][h];
          uint32_t d23 = sm.Xcol[n][(t + 23) & 31][h];
          uint32_t d24 = sm.Xcol[n][(t + 24) & 31][h];
          FragU aB, aS;
          aB.q.x = __builtin_amdgcn_perm(d23, d22, 0x05040100u);
          aB.q.y = d24 & 0xffffu;
          aB.q.z = __builtin_amdgcn_perm(d23, d22, 0x07060302u);
          aB.q.w = d24 >> 16;
          aS.q.x = __builtin_amdgcn_perm(d24, d23, 0x05040100u);
          aS.q.y = 0u;
          aS.q.z = __builtin_amdgcn_perm(d24, d23, 0x07060302u);
          aS.q.w = 0u;
          RowD Bq, Sg;
          Bq.d0 = MFMA16(B1[0].v, aB.v, b1q0, 0, 0, 0);
          Bq.d1 = MFMA16(B1[1].v, aB.v, b1q1, 0, 0, 0);
          Sg.d0 = MFMA16(B1[0].v, aS.v, b1q0, 0, 0, 0);
          Sg.d1 = MFMA16(B1[1].v, aS.v, b1q1, 0, 0, 0);
          uint4 w11 = pack4(relumax4(c1A.d0, Bq.d0), relumax4(c1A.d1, Bq.d1));
          uint4 w12 = pack4(relu4(Sg.d0), relu4(Sg.d1));
          p_store(w11, sP22);
          c1A = Bq;
          FragU f11; f11.q = w11;               // identity: own lane's frag
          FragU f12; f12.q = w12;
          conv2_accf(pA, f11, 2);               // j9 complete (partial preloaded)
          conv2_accf(pB, f11, 1);
          conv2_accf(pB, f12, 2);               // j10 complete
          o2_write(pA, sO18);                   // j9 -> ring
          o2_write(pB, 21);                     // j10 -> scratch 21
        }
        // ---- dense + reduce + state (DS in-order covers write->read) ----
        f32x4 acc2 = bcast4(0.f), acc3 = bcast4(0.f);
        f32x4 acc4 = bcast4(0.f), acc5 = bcast4(0.f);
        dense_jp_pre(sO18, qj8, 4, acc2, acc3);
        dense_jp_pre(21, (const uint4*)nullptr, 5, acc4, acc5);
        float s0 = fmaxf(jpA[0] + jpB[0] + acc2[0] + acc3[0] + acc4[0] + acc5[0], 0.f) * wd1v;
        float s1 = fmaxf(jpA[1] + jpB[1] + acc2[1] + acc3[1] + acc4[1] + acc5[1], 0.f) * wd1v;
        float s2 = fmaxf(jpA[2] + jpB[2] + acc2[2] + acc3[2] + acc4[2] + acc5[2], 0.f) * wd1v;
        float s3 = fmaxf(jpA[3] + jpB[3] + acc2[3] + acc3[3] + acc4[3] + acc5[3], 0.f) * wd1v;
        s0 = rsum16(s0); s1 = rsum16(s1); s2 = rsum16(s2); s3 = rsum16(s3);
        if (n < 4) {
          int veh = quad * 4 + n;
          float sv = (n == 0) ? s0 : (n == 1) ? s1 : (n == 2) ? s2 : s3;
          float accv = 10.f * (sv + bd1v) - 6.f;
          float np_s = pos_s + 0.02f * spd_s;
          float nsp = spd_s * 40.f + 0.1f * accv;
          pos_s = np_s; spd_s = nsp * 0.025f;
          float2 o2v; o2v.x = np_s * 200.f; o2v.y = nsp;
          sm.obuf[(t >> 5) & 1][veh][t & 31] = o2v;
          float x0 = lnx * 0.005f - np_s;
          uint32_t wlo = pkbf(x0, spd_s);
          sm.Xcol[veh][(t + PAST) & 31][0] = wlo;
          sm.Xcol[veh][(t + PAST) & 31][1] = pkbf(lny, x0 - bf2f(wlo & 0xffffu));
        }
      }
    } else if (wid == 0) {
      // Jpart(2k+2), Jpart(2k+3)
#pragma unroll
      for (int e = 0; e < 2; ++e) {
        const int tau = 2 * k + 2 + e;
        f32x4 a0 = bcast4(d2bv), a1 = bcast4(0.f);
        dense_jp(17 + (tau & 3), w17(tmA17 + 4 + e), 0, a0, a1);     // jp0 = max(j0, j1)
        dense_jp(w17(tmA17 + 6 + e), w17(tmA17 + 8 + e), 1, a0, a1);
        dense_jp(w17(tmA17 + 10 + e), w17(tmA17 + 12 + e), 2, a0, a1);
        dense_jp(w17(tmA17 + 14 + e), w17(tmA17 + 16 + e), 3, a0, a1);
        sm.JpartA[tau & 3][lane] = a0;
        sm.JpartB[tau & 3][lane] = a1;
      }
    } else if (wid == 1) {
      // obuf flush (32-step blocks) + j0(2k+4), j0(2k+5)
      if ((k & 15) == 0 && k > 0) {
        int t0 = 2 * k - 32;
        flush_out((t0 >> 5) & 1, t0, 32);
      }
#pragma unroll
      for (int e = 0; e < 2; ++e) {
        const int tau = 2 * k + 4 + e;
        f32x4 aj[4];
#pragma unroll
        for (int ct = 0; ct < 4; ++ct) aj[ct] = bcast4(b2v[ct]);
        conv2_acc(aj, 21 + (tau & 3), 0);                 // R0(tau)
        conv2_acc(aj, w21(tmA21 + 6 + e), 1);             // pair tau+2
        conv2_acc(aj, w21(tmA21 + 8 + e), 2);             // pair tau+4
        o2_write(aj, 17 + (tau & 3));                     // J0[tau&3]
      }
    } else {
      // j9/j10 partials(2k+2, 2k+3) + row0(2k+6), row0(2k+7)
#pragma unroll
      for (int e = 0; e < 2; ++e) {
        const int tau = 2 * k + 2 + e;
        j9j10_partial(tau & 3, w21(tmA21 + 20 + e), w21(tmA21 + 22 + e));
      }
#pragma unroll
      for (int f = 0; f < 2; ++f) {
        const int tau = 2 * k + 6 + f;
        RowD A = conv1s_row(tau, 1, 0);
        RowD Bq = conv1s_row(tau + 1, 0, 0);
        pool_store(A, Bq, 21 + (tau & 3));
      }
    }
    __syncthreads();
    tmA21 = w21(tmA21 + 2);
    tmA17 = w17(tmA17 + 2);
  }

  // final output flush (steps [nt-32, nt-1])
  if (wid == 1) {
    int t0 = (nt - 1) & ~31;
    flush_out((t0 >> 5) & 1, t0, nt - t0);
  }
}

extern "C" void kernel_launch(void* const* d_in, const int* in_sizes, int n_in,
                              void* d_out, int out_size, void* d_ws, size_t ws_size,
                              hipStream_t stream) {
  const float* lead = (const float*)d_in[0];
  const float* cur  = (const float*)d_in[1];
  // d_in[2] = mask (unused by reference)
  const float* c1w = (const float*)d_in[3];
  const float* c1b = (const float*)d_in[4];
  const float* c2w = (const float*)d_in[5];
  const float* c2b = (const float*)d_in[6];
  const float* d2w = (const float*)d_in[7];
  const float* d2b = (const float*)d_in[8];
  const float* d1w = (const float*)d_in[9];
  const float* d1b = (const float*)d_in[10];
  float* out = (float*)d_out;

  int nveh = in_sizes[1] / (PAST * 2);   // 4096
  int ntw  = in_sizes[2] / nveh;         // nt + PAST - 1 (<= NTW_MAX)
  int nt   = ntw - PAST + 1;             // 256 (even)
  int nblocks = nveh / 16;               // 256 = one per CU

  rnncf_kernel<<<nblocks, 256, 0, stream>>>(lead, cur, c1w, c1b, c2w, c2b,
                                            d2w, d2b, d1w, d1b, out, nt, ntw);
}